// Round 15
// baseline (3350.939 us; speedup 1.0000x reference)
//
#include <hip/hip_runtime.h>

typedef unsigned int u32;
typedef unsigned long long u64;

#define Bc 256
#define Tc 325
#define NSc 39
#define COc 64
#define NCc 20
#define ESc 117
#define ETc 648

// workspace layout in 4-byte units
#define WS_ROFF_S 0        // 40 ints
#define WS_EDGE_S 64       // 117 int2
#define WS_DINV_S 304      // 39 f
#define WS_ROFF_T 352      // 326 ints
#define WS_EDGE_T 680      // 648 int2
#define WS_DINV_T 1976     // 325 f
#define WS_W1T    2304     // 49920 f  (fc1_w transposed [20][2496])
#define WS_W2T    52224    // 416000 f (tfc1_w transposed [20][20800])

// ---------------- prep: CSR (by dst, interleaved {src, nrm}) ----------------
__global__ void prep_graph(const int* __restrict__ eiS, const int* __restrict__ eiT,
                           int* __restrict__ wsI, float* __restrict__ wsF) {
  const int which = blockIdx.x;
  const int* ei = which ? eiT : eiS;
  const int nE = which ? ETc : ESc;
  const int nN = which ? Tc : NSc;
  int* roff = wsI + (which ? WS_ROFF_T : WS_ROFF_S);
  int2* edge = (int2*)(wsI + (which ? WS_EDGE_T : WS_EDGE_S));
  float* dinv = wsF + (which ? WS_DINV_T : WS_DINV_S);
  const int* src = ei;
  const int* dst = ei + nE;
  for (int n = threadIdx.x; n < nN; n += blockDim.x) {
    int deg = 0, before = 0;
    for (int e = 0; e < nE; ++e) { deg += (dst[e] == n); before += (dst[e] < n); }
    roff[n] = before;
    if (n == nN - 1) roff[nN] = before + deg;
    dinv[n] = (deg > 0) ? (1.0f / sqrtf((float)deg)) : 0.0f;
  }
  __syncthreads();
  for (int n = threadIdx.x; n < nN; n += blockDim.x) {
    int cur = roff[n];
    float dn = dinv[n];
    for (int e = 0; e < nE; ++e) {
      if (dst[e] == n) {
        edge[cur] = make_int2(src[e], __float_as_int(dinv[src[e]] * dn));
        ++cur;
      }
    }
  }
}

// ---------------- prep: transpose both fc weights ----------------
__global__ void prep_w(const float* __restrict__ w1, float* __restrict__ w1T,
                       const float* __restrict__ w2, float* __restrict__ w2T) {
  int i = blockIdx.x * 256 + threadIdx.x;
  if (i < NCc * Tc * COc) {
    int j = i / (Tc * COc);
    int p = i - j * (Tc * COc);
    w2T[i] = w2[p * NCc + j];
  }
  if (i < NCc * NSc * COc) {
    int j = i / (NSc * COc);
    int p = i - j * (NSc * COc);
    w1T[i] = w1[p * NCc + j];
  }
}

// ---------------- fused kernel: 1 batch per block, 768 threads (12 waves) ----------------
__global__ __launch_bounds__(768)
void lif_fused(const float* __restrict__ data,
               const int* __restrict__ roffSg, const int2* __restrict__ edgeSg,
               const int* __restrict__ roffTg, const int2* __restrict__ edgeTg,
               const float* __restrict__ c1w, const float* __restrict__ c1b,
               const float* __restrict__ c2w, const float* __restrict__ c2b,
               const float* __restrict__ w1T, const float* __restrict__ f1b,
               const float* __restrict__ w2T, const float* __restrict__ tf1b,
               float* __restrict__ out)
{
  __shared__ u64 spk[NSc * Tc];                  // 101400 B: A=[t][39], B=[s][325]
  __shared__ __align__(16) float fAB[9984];      // A: [16][39][16] / B: [325][20] t-major
  __shared__ float partials[780];                // [4jg][3ith][13ds][5jj]
  __shared__ float cwL[1024];
  __shared__ float outS_l[NCc];
  __shared__ int roffS[NSc + 1];
  __shared__ int2 edgeS[ESc];
  __shared__ int roffT[Tc + 1];
  __shared__ int2 edgeT[ETc];

  const int tid = threadIdx.x;
  const int lane = tid & 63;
  const int wv = tid >> 6;             // 0..11
  const int b = blockIdx.x;
  const int lhalf = lane >> 5;
  const int lbit = lane & 31;
  const float* dbase = data + (size_t)b * (2 * NSc * 2 * Tc);

  for (int i = tid; i < NSc + 1; i += 768) roffS[i] = roffSg[i];
  for (int i = tid; i < ESc; i += 768) edgeS[i] = edgeSg[i];
  for (int i = tid; i < Tc + 1; i += 768) roffT[i] = roffTg[i];
  for (int i = tid; i < ETc; i += 768) edgeT[i] = edgeTg[i];
  for (int i = tid; i < 1024; i += 768) cwL[i] = c1w[i];

  // fc decomposition: 4 j-groups of 5 x 3 i-thirds; owned LIF outputs ja=wv, jb=12+wv (wv<8)
  const int jg = wv / 3, ith = wv % 3;
  const int ja = wv, jb = 12 + wv;
  const int jag = ja / 5, jaj = ja % 5;
  const int jbg = jb / 5, jbj = jb % 5;

  // ============ Phase A: spatial, per 13-t chunk: {stage, hops, conv+LIF, fc GEMM, h-LIF} ============
  {
    const float bcv = c1b[lane];
    float cm[4] = {0, 0, 0, 0};
    const int iBase = ith * 13;
    const float* wq0 = w1T + (jg * 5 + 0) * (NSc * COc) + iBase * COc + lane;
    const float* wq1 = w1T + (jg * 5 + 1) * (NSc * COc) + iBase * COc + lane;
    const float* wq2 = w1T + (jg * 5 + 2) * (NSc * COc) + iBase * COc + lane;
    const float* wq3 = w1T + (jg * 5 + 3) * (NSc * COc) + iBase * COc + lane;
    const float* wq4 = w1T + (jg * 5 + 4) * (NSc * COc) + iBase * COc + lane;
    const float ba = f1b[ja];
    const float bb = (wv < 8) ? f1b[jb] : 0.0f;
    float hma = 0, hsa = 0, hmb = 0, hsb = 0;
    __syncthreads();

#pragma unroll 1
    for (int ch = 0; ch < 25; ++ch) {
      const int t0 = ch * 13;
      // stage x: fA[c][n][dt16]
#pragma unroll
      for (int it = 0; it < 4; ++it) {
        int idx = tid + it * 768;
        if (idx < 2496) {
          int n = idx >> 6, c = (idx >> 4) & 3, dt = idx & 15;
          float v = 0.0f;
          if (dt < 13) v = dbase[(n + (c >> 1) * NSc) * 650 + (c & 1) * 325 + t0 + dt];
          fAB[c * 624 + n * 16 + dt] = v;
        }
      }
      __syncthreads();
      // 3 hops
#pragma unroll
      for (int k = 1; k <= 3; ++k) {
#pragma unroll
        for (int it = 0; it < 4; ++it) {
          int idx = tid + it * 768;
          if (idx < 2496) {
            int n = idx >> 6, c = (idx >> 4) & 3, dt = idx & 15;
            float v = 0.0f;
            for (int e = roffS[n]; e < roffS[n + 1]; ++e) {
              int2 ed = edgeS[e];
              v = fmaf(__int_as_float(ed.y), fAB[((k - 1) * 4 + c) * 624 + ed.x * 16 + dt], v);
            }
            fAB[(k * 4 + c) * 624 + n * 16 + dt] = v;
          }
        }
        __syncthreads();
      }
      // conv + LIF + ballot -> spk[t][i]
      {
        float wcr[16];
#pragma unroll
        for (int r = 0; r < 16; ++r) wcr[r] = cwL[r * 64 + lane];
#pragma unroll
        for (int q = 0; q < 4; ++q) {
          int i = wv + 12 * q;
          if (i < NSc) {
            float za[13];
#pragma unroll
            for (int dt = 0; dt < 13; ++dt) za[dt] = bcv;
#pragma unroll
            for (int r = 0; r < 16; ++r) {
              const float* fp = &fAB[r * 624 + i * 16];
              float w = wcr[r];
              float4 a0 = *(const float4*)fp;
              float4 a1 = *(const float4*)(fp + 4);
              float4 a2 = *(const float4*)(fp + 8);
              float a3 = fp[12];
              za[0] = fmaf(a0.x, w, za[0]);   za[1] = fmaf(a0.y, w, za[1]);
              za[2] = fmaf(a0.z, w, za[2]);   za[3] = fmaf(a0.w, w, za[3]);
              za[4] = fmaf(a1.x, w, za[4]);   za[5] = fmaf(a1.y, w, za[5]);
              za[6] = fmaf(a1.z, w, za[6]);   za[7] = fmaf(a1.w, w, za[7]);
              za[8] = fmaf(a2.x, w, za[8]);   za[9] = fmaf(a2.y, w, za[9]);
              za[10] = fmaf(a2.z, w, za[10]); za[11] = fmaf(a2.w, w, za[11]);
              za[12] = fmaf(a3, w, za[12]);
            }
#pragma unroll
            for (int dt = 0; dt < 13; ++dt) {
              float old = cm[q];
              float m = (old * 0.2f) * ((old > 0.5f) ? 0.0f : 1.0f) + za[dt];
              cm[q] = m;
              u64 wd = __ballot(m > 0.5f);
              if (lane == 0) spk[(t0 + dt) * NSc + i] = wd;
            }
          }
        }
      }
      __syncthreads();
      // fc GEMM over chunk: 13 i per wave
      float ya[13][5];
#pragma unroll
      for (int ds = 0; ds < 13; ++ds)
#pragma unroll
        for (int jj = 0; jj < 5; ++jj) ya[ds][jj] = 0.0f;
#pragma unroll 1
      for (int ii = 0; ii < 13; ++ii) {
        const int i = iBase + ii;
        float w0 = wq0[ii * COc];
        float w1 = wq1[ii * COc];
        float w2 = wq2[ii * COc];
        float w3 = wq3[ii * COc];
        float w4 = wq4[ii * COc];
#pragma unroll
        for (int ds = 0; ds < 13; ++ds) {
          u32 wrd = ((const u32*)spk)[((t0 + ds) * NSc + i) * 2 + lhalf];
          float g = (float)((wrd >> lbit) & 1u);
          ya[ds][0] = fmaf(g, w0, ya[ds][0]);
          ya[ds][1] = fmaf(g, w1, ya[ds][1]);
          ya[ds][2] = fmaf(g, w2, ya[ds][2]);
          ya[ds][3] = fmaf(g, w3, ya[ds][3]);
          ya[ds][4] = fmaf(g, w4, ya[ds][4]);
        }
      }
#pragma unroll
      for (int off = 32; off >= 1; off >>= 1)
#pragma unroll
        for (int ds = 0; ds < 13; ++ds)
#pragma unroll
          for (int jj = 0; jj < 5; ++jj)
            ya[ds][jj] += __shfl_xor(ya[ds][jj], off, 64);
      if (lane == 0) {
#pragma unroll
        for (int ds = 0; ds < 13; ++ds)
#pragma unroll
          for (int jj = 0; jj < 5; ++jj)
            partials[(jg * 3 + ith) * 65 + ds * 5 + jj] = ya[ds][jj];
      }
      __syncthreads();
      // h-LIF for owned outputs (3-way partial sum)
#pragma unroll
      for (int ds = 0; ds < 13; ++ds) {
        float y0 = partials[(jag * 3 + 0) * 65 + ds * 5 + jaj]
                 + partials[(jag * 3 + 1) * 65 + ds * 5 + jaj]
                 + partials[(jag * 3 + 2) * 65 + ds * 5 + jaj] + ba;
        hma = (hma * 0.2f) * ((hma > 0.5f) ? 0.0f : 1.0f) + y0;
        hsa += (hma > 0.5f) ? 1.0f : 0.0f;
        if (wv < 8) {
          float y1 = partials[(jbg * 3 + 0) * 65 + ds * 5 + jbj]
                   + partials[(jbg * 3 + 1) * 65 + ds * 5 + jbj]
                   + partials[(jbg * 3 + 2) * 65 + ds * 5 + jbj] + bb;
          hmb = (hmb * 0.2f) * ((hmb > 0.5f) ? 0.0f : 1.0f) + y1;
          hsb += (hmb > 0.5f) ? 1.0f : 0.0f;
        }
      }
      __syncthreads();
    }
    if (lane == 0) {
      outS_l[ja] = hsa / (float)Tc;
      if (wv < 8) outS_l[jb] = hsb / (float)Tc;
    }
  }
  __syncthreads();

  // ============ Phase B1: temporal conv chain -> spk[s][i], t-major [t][20] layout ============
  {
    float wc[16];
#pragma unroll
    for (int r = 0; r < 16; ++r) wc[r] = c2w[r * COc + lane];
    const float bcv = c2b[lane];
    float tm[28];
#pragma unroll
    for (int q = 0; q < 28; ++q) tm[q] = 0.0f;

#pragma unroll 1
    for (int s = 0; s < NSc; ++s) {
      // stage x_s: fAB[t*20 + c]
#pragma unroll
      for (int it = 0; it < 2; ++it) {
        int idx = tid + it * 768;
        if (idx < Tc * 4) {
          int c = idx / Tc, t = idx - c * Tc;
          fAB[t * 20 + c] = dbase[(s + (c >> 1) * NSc) * 650 + (c & 1) * 325 + t];
        }
      }
      __syncthreads();
#pragma unroll
      for (int k = 1; k <= 3; ++k) {
#pragma unroll
        for (int it = 0; it < 2; ++it) {
          int idx = tid + it * 768;
          if (idx < Tc * 4) {
            int t = idx >> 2, c = idx & 3;
            float v = 0.0f;
            for (int e = roffT[t]; e < roffT[t + 1]; ++e) {
              int2 ed = edgeT[e];
              v = fmaf(__int_as_float(ed.y), fAB[ed.x * 20 + (k - 1) * 4 + c], v);
            }
            fAB[t * 20 + k * 4 + c] = v;
          }
        }
        __syncthreads();
      }
      // conv + LIF + ballot: vectorized b128 reads from [i][20]
#pragma unroll
      for (int q = 0; q < 28; ++q) {
        int i = wv + 12 * q;
        if (i < Tc) {
          const float4* f4 = (const float4*)&fAB[i * 20];
          float4 f0 = f4[0], f1 = f4[1], f2 = f4[2], f3 = f4[3];
          float acc = bcv;
          acc = fmaf(f0.x, wc[0], acc);  acc = fmaf(f0.y, wc[1], acc);
          acc = fmaf(f0.z, wc[2], acc);  acc = fmaf(f0.w, wc[3], acc);
          acc = fmaf(f1.x, wc[4], acc);  acc = fmaf(f1.y, wc[5], acc);
          acc = fmaf(f1.z, wc[6], acc);  acc = fmaf(f1.w, wc[7], acc);
          acc = fmaf(f2.x, wc[8], acc);  acc = fmaf(f2.y, wc[9], acc);
          acc = fmaf(f2.z, wc[10], acc); acc = fmaf(f2.w, wc[11], acc);
          acc = fmaf(f3.x, wc[12], acc); acc = fmaf(f3.y, wc[13], acc);
          acc = fmaf(f3.z, wc[14], acc); acc = fmaf(f3.w, wc[15], acc);
          float old = tm[q];
          float m = (old * 0.2f) * ((old > 0.5f) ? 0.0f : 1.0f) + acc;
          tm[q] = m;
          u64 wd = __ballot(m > 0.5f);
          if (lane == 0) spk[s * Tc + i] = wd;
        }
      }
      __syncthreads();
    }
  }

  // ============ Phase B2: temporal fc binary GEMM + h-LIF + combine ============
  {
    const int iBase = ith * 108;
    const int iN = (ith == 2) ? 109 : 108;
    const float* wq0 = w2T + (size_t)(jg * 5 + 0) * (Tc * COc) + iBase * COc + lane;
    const float* wq1 = w2T + (size_t)(jg * 5 + 1) * (Tc * COc) + iBase * COc + lane;
    const float* wq2 = w2T + (size_t)(jg * 5 + 2) * (Tc * COc) + iBase * COc + lane;
    const float* wq3 = w2T + (size_t)(jg * 5 + 3) * (Tc * COc) + iBase * COc + lane;
    const float* wq4 = w2T + (size_t)(jg * 5 + 4) * (Tc * COc) + iBase * COc + lane;
    const float ba = tf1b[ja];
    const float bb = (wv < 8) ? tf1b[jb] : 0.0f;
    float hma = 0, hsa = 0, hmb = 0, hsb = 0;

#pragma unroll 1
    for (int chn = 0; chn < 3; ++chn) {
      const int s0 = chn * 13;
      float ya[13][5];
#pragma unroll
      for (int ds = 0; ds < 13; ++ds)
#pragma unroll
        for (int jj = 0; jj < 5; ++jj) ya[ds][jj] = 0.0f;

#pragma unroll 1
      for (int ii = 0; ii < iN; ++ii) {
        const int i = iBase + ii;
        float w0 = wq0[(size_t)ii * COc];
        float w1 = wq1[(size_t)ii * COc];
        float w2 = wq2[(size_t)ii * COc];
        float w3 = wq3[(size_t)ii * COc];
        float w4 = wq4[(size_t)ii * COc];
#pragma unroll
        for (int ds = 0; ds < 13; ++ds) {
          u32 wrd = ((const u32*)spk)[((s0 + ds) * Tc + i) * 2 + lhalf];
          float g = (float)((wrd >> lbit) & 1u);
          ya[ds][0] = fmaf(g, w0, ya[ds][0]);
          ya[ds][1] = fmaf(g, w1, ya[ds][1]);
          ya[ds][2] = fmaf(g, w2, ya[ds][2]);
          ya[ds][3] = fmaf(g, w3, ya[ds][3]);
          ya[ds][4] = fmaf(g, w4, ya[ds][4]);
        }
      }
#pragma unroll
      for (int off = 32; off >= 1; off >>= 1)
#pragma unroll
        for (int ds = 0; ds < 13; ++ds)
#pragma unroll
          for (int jj = 0; jj < 5; ++jj)
            ya[ds][jj] += __shfl_xor(ya[ds][jj], off, 64);
      if (lane == 0) {
#pragma unroll
        for (int ds = 0; ds < 13; ++ds)
#pragma unroll
          for (int jj = 0; jj < 5; ++jj)
            partials[(jg * 3 + ith) * 65 + ds * 5 + jj] = ya[ds][jj];
      }
      __syncthreads();
#pragma unroll
      for (int ds = 0; ds < 13; ++ds) {
        float y0 = partials[(jag * 3 + 0) * 65 + ds * 5 + jaj]
                 + partials[(jag * 3 + 1) * 65 + ds * 5 + jaj]
                 + partials[(jag * 3 + 2) * 65 + ds * 5 + jaj] + ba;
        hma = (hma * 0.2f) * ((hma > 0.5f) ? 0.0f : 1.0f) + y0;
        hsa += (hma > 0.5f) ? 1.0f : 0.0f;
        if (wv < 8) {
          float y1 = partials[(jbg * 3 + 0) * 65 + ds * 5 + jbj]
                   + partials[(jbg * 3 + 1) * 65 + ds * 5 + jbj]
                   + partials[(jbg * 3 + 2) * 65 + ds * 5 + jbj] + bb;
          hmb = (hmb * 0.2f) * ((hmb > 0.5f) ? 0.0f : 1.0f) + y1;
          hsb += (hmb > 0.5f) ? 1.0f : 0.0f;
        }
      }
      __syncthreads();
    }
    if (lane == 0) {
      out[b * NCc + ja] = (outS_l[ja] + hsa / (float)NSc) * 0.5f;
      if (wv < 8)
        out[b * NCc + jb] = (outS_l[jb] + hsb / (float)NSc) * 0.5f;
    }
  }
}

extern "C" void kernel_launch(void* const* d_in, const int* in_sizes, int n_in,
                              void* d_out, int out_size, void* d_ws, size_t ws_size,
                              hipStream_t stream) {
  const float* data = (const float*)d_in[0];
  const int*   eiS  = (const int*)d_in[1];
  const int*   eiT  = (const int*)d_in[2];
  const float* c1w  = (const float*)d_in[3];
  const float* c1b  = (const float*)d_in[4];
  const float* c2w  = (const float*)d_in[5];
  const float* c2b  = (const float*)d_in[6];
  const float* f1w  = (const float*)d_in[7];
  const float* f1b  = (const float*)d_in[8];
  const float* tf1w = (const float*)d_in[9];
  const float* tf1b = (const float*)d_in[10];
  float* out = (float*)d_out;
  int* wsI = (int*)d_ws;
  float* wsF = (float*)d_ws;

  prep_graph<<<2, 256, 0, stream>>>(eiS, eiT, wsI, wsF);
  prep_w<<<(NCc * Tc * COc + 255) / 256, 256, 0, stream>>>(f1w, wsF + WS_W1T,
                                                           tf1w, wsF + WS_W2T);
  lif_fused<<<Bc, 768, 0, stream>>>(data,
                                    wsI + WS_ROFF_S, (const int2*)(wsI + WS_EDGE_S),
                                    wsI + WS_ROFF_T, (const int2*)(wsI + WS_EDGE_T),
                                    c1w, c1b, c2w, c2b,
                                    wsF + WS_W1T, f1b, wsF + WS_W2T, tf1b,
                                    out);
}

// Round 16
// 1412.527 us; speedup vs baseline: 2.3723x; 2.3723x over previous
//
#include <hip/hip_runtime.h>

typedef unsigned int u32;
typedef unsigned long long u64;

#define Bc 256
#define Tc 325
#define NSc 39
#define COc 64
#define NCc 20
#define ESc 117
#define ETc 648

// workspace layout in 4-byte units
#define WS_ROFF_S 0        // 40 ints
#define WS_EDGE_S 64       // 117 int2
#define WS_DINV_S 304      // 39 f
#define WS_ROFF_T 352      // 326 ints
#define WS_EDGE_T 680      // 648 int2
#define WS_DINV_T 1976     // 325 f
#define WS_W1T    2304     // 49920 f  (fc1_w transposed [20][2496])
#define WS_W2T    52224    // 416000 f (tfc1_w transposed [20][20800])

// ---------------- prep: CSR (by dst, interleaved {src, nrm}) ----------------
__global__ void prep_graph(const int* __restrict__ eiS, const int* __restrict__ eiT,
                           int* __restrict__ wsI, float* __restrict__ wsF) {
  const int which = blockIdx.x;
  const int* ei = which ? eiT : eiS;
  const int nE = which ? ETc : ESc;
  const int nN = which ? Tc : NSc;
  int* roff = wsI + (which ? WS_ROFF_T : WS_ROFF_S);
  int2* edge = (int2*)(wsI + (which ? WS_EDGE_T : WS_EDGE_S));
  float* dinv = wsF + (which ? WS_DINV_T : WS_DINV_S);
  const int* src = ei;
  const int* dst = ei + nE;
  for (int n = threadIdx.x; n < nN; n += blockDim.x) {
    int deg = 0, before = 0;
    for (int e = 0; e < nE; ++e) { deg += (dst[e] == n); before += (dst[e] < n); }
    roff[n] = before;
    if (n == nN - 1) roff[nN] = before + deg;
    dinv[n] = (deg > 0) ? (1.0f / sqrtf((float)deg)) : 0.0f;
  }
  __syncthreads();
  for (int n = threadIdx.x; n < nN; n += blockDim.x) {
    int cur = roff[n];
    float dn = dinv[n];
    for (int e = 0; e < nE; ++e) {
      if (dst[e] == n) {
        edge[cur] = make_int2(src[e], __float_as_int(dinv[src[e]] * dn));
        ++cur;
      }
    }
  }
}

// ---------------- prep: transpose both fc weights ----------------
__global__ void prep_w(const float* __restrict__ w1, float* __restrict__ w1T,
                       const float* __restrict__ w2, float* __restrict__ w2T) {
  int i = blockIdx.x * 256 + threadIdx.x;
  if (i < NCc * Tc * COc) {
    int j = i / (Tc * COc);
    int p = i - j * (Tc * COc);
    w2T[i] = w2[p * NCc + j];
  }
  if (i < NCc * NSc * COc) {
    int j = i / (NSc * COc);
    int p = i - j * (NSc * COc);
    w1T[i] = w1[p * NCc + j];
  }
}

// ---------------- fused kernel: 1 batch per block, 512 threads ----------------
__global__ __launch_bounds__(512) __attribute__((amdgpu_waves_per_eu(2, 2)))
void lif_fused(const float* __restrict__ data,
               const int* __restrict__ roffSg, const int2* __restrict__ edgeSg,
               const int* __restrict__ roffTg, const int2* __restrict__ edgeTg,
               const float* __restrict__ c1w, const float* __restrict__ c1b,
               const float* __restrict__ c2w, const float* __restrict__ c2b,
               const float* __restrict__ w1T, const float* __restrict__ f1b,
               const float* __restrict__ w2T, const float* __restrict__ tf1b,
               float* __restrict__ out)
{
  __shared__ u64 spk[NSc * Tc];                  // 101400 B: A=[t][39], B=[s][325]
  __shared__ __align__(16) float fAB[13000];     // A: [16][39][16] / B: 2 planes [325][20]
  __shared__ float partials[520];
  __shared__ float outS_l[NCc];
  __shared__ int roffS[NSc + 1];
  __shared__ int2 edgeS[ESc];
  __shared__ int roffT[Tc + 1];
  __shared__ int2 edgeT[ETc];

  const int tid = threadIdx.x;
  const int lane = tid & 63;
  const int wv = tid >> 6;             // 0..7
  const int b = blockIdx.x;
  const int lhalf = lane >> 5;
  const int lbit = lane & 31;
  const float* dbase = data + (size_t)b * (2 * NSc * 2 * Tc);

  for (int i = tid; i < NSc + 1; i += 512) roffS[i] = roffSg[i];
  for (int i = tid; i < ESc; i += 512) edgeS[i] = edgeSg[i];
  for (int i = tid; i < Tc + 1; i += 512) roffT[i] = roffTg[i];
  for (int i = tid; i < ETc; i += 512) edgeT[i] = edgeTg[i];

  // common decomposition for fc GEMM + owned LIF outputs
  const int jg = wv >> 1, ih = wv & 1;
  const int ja = wv, jb = wv + 8, jc = wv + 16;
  const int jag = ja / 5, jaj = ja % 5;
  const int jbg = jb / 5, jbj = jb % 5;
  const int jcg = jc / 5, jcj = jc % 5;

  // ============ Phase A: spatial, per 13-t chunk: {stage, hops, conv+LIF, fc GEMM, h-LIF} ============
  {
    const float bcv = c1b[lane];
    float cm[5] = {0, 0, 0, 0, 0};
    const int iBase = ih * 20, iN = ih ? 19 : 20;
    const float* wq0 = w1T + (jg * 5 + 0) * (NSc * COc) + iBase * COc + lane;
    const float* wq1 = w1T + (jg * 5 + 1) * (NSc * COc) + iBase * COc + lane;
    const float* wq2 = w1T + (jg * 5 + 2) * (NSc * COc) + iBase * COc + lane;
    const float* wq3 = w1T + (jg * 5 + 3) * (NSc * COc) + iBase * COc + lane;
    const float* wq4 = w1T + (jg * 5 + 4) * (NSc * COc) + iBase * COc + lane;
    const float ba = f1b[ja], bb = f1b[jb];
    const float bc2 = (wv < 4) ? f1b[jc] : 0.0f;
    float hma = 0, hsa = 0, hmb = 0, hsb = 0, hmc = 0, hsc = 0;
    __syncthreads();

#pragma unroll 1
    for (int ch = 0; ch < 25; ++ch) {
      const int t0 = ch * 13;
      // stage x: fA[c][n][dt16]
#pragma unroll
      for (int it = 0; it < 5; ++it) {
        int idx = tid + it * 512;
        if (idx < 2496) {
          int n = idx >> 6, c = (idx >> 4) & 3, dt = idx & 15;
          float v = 0.0f;
          if (dt < 13) v = dbase[(n + (c >> 1) * NSc) * 650 + (c & 1) * 325 + t0 + dt];
          fAB[c * 624 + n * 16 + dt] = v;
        }
      }
      __syncthreads();
      // 3 hops
#pragma unroll
      for (int k = 1; k <= 3; ++k) {
#pragma unroll
        for (int it = 0; it < 5; ++it) {
          int idx = tid + it * 512;
          if (idx < 2496) {
            int n = idx >> 6, c = (idx >> 4) & 3, dt = idx & 15;
            float v = 0.0f;
            for (int e = roffS[n]; e < roffS[n + 1]; ++e) {
              int2 ed = edgeS[e];
              v = fmaf(__int_as_float(ed.y), fAB[((k - 1) * 4 + c) * 624 + ed.x * 16 + dt], v);
            }
            fAB[(k * 4 + c) * 624 + n * 16 + dt] = v;
          }
        }
        __syncthreads();
      }
      // conv + LIF + ballot -> spk[t][i]
      {
        float wcr[16];
#pragma unroll
        for (int r = 0; r < 16; ++r) wcr[r] = c1w[r * COc + lane];
#pragma unroll
        for (int q = 0; q < 5; ++q) {
          int i = wv + 8 * q;
          if (i < NSc) {
            float za[13];
#pragma unroll
            for (int dt = 0; dt < 13; ++dt) za[dt] = bcv;
#pragma unroll
            for (int r = 0; r < 16; ++r) {
              const float* fp = &fAB[r * 624 + i * 16];
              float w = wcr[r];
              float4 a0 = *(const float4*)fp;
              float4 a1 = *(const float4*)(fp + 4);
              float4 a2 = *(const float4*)(fp + 8);
              float a3 = fp[12];
              za[0] = fmaf(a0.x, w, za[0]);   za[1] = fmaf(a0.y, w, za[1]);
              za[2] = fmaf(a0.z, w, za[2]);   za[3] = fmaf(a0.w, w, za[3]);
              za[4] = fmaf(a1.x, w, za[4]);   za[5] = fmaf(a1.y, w, za[5]);
              za[6] = fmaf(a1.z, w, za[6]);   za[7] = fmaf(a1.w, w, za[7]);
              za[8] = fmaf(a2.x, w, za[8]);   za[9] = fmaf(a2.y, w, za[9]);
              za[10] = fmaf(a2.z, w, za[10]); za[11] = fmaf(a2.w, w, za[11]);
              za[12] = fmaf(a3, w, za[12]);
            }
#pragma unroll
            for (int dt = 0; dt < 13; ++dt) {
              float old = cm[q];
              float m = (old * 0.2f) * ((old > 0.5f) ? 0.0f : 1.0f) + za[dt];
              cm[q] = m;
              u64 wd = __ballot(m > 0.5f);
              if (lane == 0) spk[(t0 + dt) * NSc + i] = wd;
            }
          }
        }
      }
      __syncthreads();
      // fc GEMM over chunk
      float ya[13][5];
#pragma unroll
      for (int ds = 0; ds < 13; ++ds)
#pragma unroll
        for (int jj = 0; jj < 5; ++jj) ya[ds][jj] = 0.0f;
#pragma unroll 1
      for (int ii = 0; ii < iN; ++ii) {
        const int i = iBase + ii;
        float w0 = wq0[ii * COc];
        float w1 = wq1[ii * COc];
        float w2 = wq2[ii * COc];
        float w3 = wq3[ii * COc];
        float w4 = wq4[ii * COc];
#pragma unroll
        for (int ds = 0; ds < 13; ++ds) {
          u32 wrd = ((const u32*)spk)[((t0 + ds) * NSc + i) * 2 + lhalf];
          float g = (float)((wrd >> lbit) & 1u);
          ya[ds][0] = fmaf(g, w0, ya[ds][0]);
          ya[ds][1] = fmaf(g, w1, ya[ds][1]);
          ya[ds][2] = fmaf(g, w2, ya[ds][2]);
          ya[ds][3] = fmaf(g, w3, ya[ds][3]);
          ya[ds][4] = fmaf(g, w4, ya[ds][4]);
        }
      }
#pragma unroll
      for (int off = 32; off >= 1; off >>= 1)
#pragma unroll
        for (int ds = 0; ds < 13; ++ds)
#pragma unroll
          for (int jj = 0; jj < 5; ++jj)
            ya[ds][jj] += __shfl_xor(ya[ds][jj], off, 64);
      if (lane == 0) {
#pragma unroll
        for (int ds = 0; ds < 13; ++ds)
#pragma unroll
          for (int jj = 0; jj < 5; ++jj)
            partials[(jg * 2 + ih) * 65 + ds * 5 + jj] = ya[ds][jj];
      }
      __syncthreads();
      // h-LIF for owned outputs
#pragma unroll
      for (int ds = 0; ds < 13; ++ds) {
        float y0 = partials[(jag * 2 + 0) * 65 + ds * 5 + jaj]
                 + partials[(jag * 2 + 1) * 65 + ds * 5 + jaj] + ba;
        hma = (hma * 0.2f) * ((hma > 0.5f) ? 0.0f : 1.0f) + y0;
        hsa += (hma > 0.5f) ? 1.0f : 0.0f;
        float y1 = partials[(jbg * 2 + 0) * 65 + ds * 5 + jbj]
                 + partials[(jbg * 2 + 1) * 65 + ds * 5 + jbj] + bb;
        hmb = (hmb * 0.2f) * ((hmb > 0.5f) ? 0.0f : 1.0f) + y1;
        hsb += (hmb > 0.5f) ? 1.0f : 0.0f;
        if (wv < 4) {
          float y2 = partials[(jcg * 2 + 0) * 65 + ds * 5 + jcj]
                   + partials[(jcg * 2 + 1) * 65 + ds * 5 + jcj] + bc2;
          hmc = (hmc * 0.2f) * ((hmc > 0.5f) ? 0.0f : 1.0f) + y2;
          hsc += (hmc > 0.5f) ? 1.0f : 0.0f;
        }
      }
      __syncthreads();
    }
    if (lane == 0) {
      outS_l[ja] = hsa / (float)Tc;
      outS_l[jb] = hsb / (float)Tc;
      if (wv < 4) outS_l[jc] = hsc / (float)Tc;
    }
  }
  __syncthreads();

  // ============ Phase B1: temporal conv chain, 2 s-steps per barrier group ============
  {
    float wc[16];
#pragma unroll
    for (int r = 0; r < 16; ++r) wc[r] = c2w[r * COc + lane];
    const float bcv = c2b[lane];
    float tm[41];
#pragma unroll
    for (int q = 0; q < 41; ++q) tm[q] = 0.0f;

#pragma unroll 1
    for (int pr = 0; pr < 20; ++pr) {
      const int sA = pr * 2;
      const int pN = (sA + 1 < NSc) ? 2 : 1;
      const int items = pN * 1300;
      // stage pN planes: fAB[p*6500 + t*20 + c]
#pragma unroll
      for (int it = 0; it < 6; ++it) {
        int idx = tid + it * 512;
        if (idx < items) {
          int p = (idx >= 1300) ? 1 : 0;
          int q2 = idx - p * 1300;
          int c = q2 / 325, t = q2 - c * 325;
          fAB[p * 6500 + t * 20 + c] =
              dbase[((sA + p) + (c >> 1) * NSc) * 650 + (c & 1) * 325 + t];
        }
      }
      __syncthreads();
      // 3 hops over both planes
#pragma unroll
      for (int k = 1; k <= 3; ++k) {
#pragma unroll
        for (int it = 0; it < 6; ++it) {
          int idx = tid + it * 512;
          if (idx < items) {
            int p = (idx >= 1300) ? 1 : 0;
            int q2 = idx - p * 1300;
            int c = q2 >> 2, t2 = q2 & 3;   // note: remap (t,c) for hop indexing
            // use (t, c) = (q2 >> 2, q2 & 3): 1300 = 325*4
            int t = c; c = t2;
            float v = 0.0f;
            for (int e = roffT[t]; e < roffT[t + 1]; ++e) {
              int2 ed = edgeT[e];
              v = fmaf(__int_as_float(ed.y), fAB[p * 6500 + ed.x * 20 + (k - 1) * 4 + c], v);
            }
            fAB[p * 6500 + t * 20 + k * 4 + c] = v;
          }
        }
        __syncthreads();
      }
      // conv + LIF (sequential over the pair) + ballot
#pragma unroll
      for (int q = 0; q < 41; ++q) {
        int i = wv + 8 * q;
        if (i < Tc) {
          float m = tm[q];
#pragma unroll
          for (int p = 0; p < 2; ++p) {
            if (p < pN) {
              const float4* f4 = (const float4*)&fAB[p * 6500 + i * 20];
              float4 f0 = f4[0], f1 = f4[1], f2 = f4[2], f3 = f4[3];
              float acc = bcv;
              acc = fmaf(f0.x, wc[0], acc);  acc = fmaf(f0.y, wc[1], acc);
              acc = fmaf(f0.z, wc[2], acc);  acc = fmaf(f0.w, wc[3], acc);
              acc = fmaf(f1.x, wc[4], acc);  acc = fmaf(f1.y, wc[5], acc);
              acc = fmaf(f1.z, wc[6], acc);  acc = fmaf(f1.w, wc[7], acc);
              acc = fmaf(f2.x, wc[8], acc);  acc = fmaf(f2.y, wc[9], acc);
              acc = fmaf(f2.z, wc[10], acc); acc = fmaf(f2.w, wc[11], acc);
              acc = fmaf(f3.x, wc[12], acc); acc = fmaf(f3.y, wc[13], acc);
              acc = fmaf(f3.z, wc[14], acc); acc = fmaf(f3.w, wc[15], acc);
              m = (m * 0.2f) * ((m > 0.5f) ? 0.0f : 1.0f) + acc;
              u64 wd = __ballot(m > 0.5f);
              if (lane == 0) spk[(sA + p) * Tc + i] = wd;
            }
          }
          tm[q] = m;
        }
      }
      __syncthreads();
    }
  }

  // ============ Phase B2: temporal fc binary GEMM + h-LIF + combine ============
  {
    const int iBase = ih * 163, iN = ih ? 162 : 163;
    const float* wq0 = w2T + (size_t)(jg * 5 + 0) * (Tc * COc) + iBase * COc + lane;
    const float* wq1 = w2T + (size_t)(jg * 5 + 1) * (Tc * COc) + iBase * COc + lane;
    const float* wq2 = w2T + (size_t)(jg * 5 + 2) * (Tc * COc) + iBase * COc + lane;
    const float* wq3 = w2T + (size_t)(jg * 5 + 3) * (Tc * COc) + iBase * COc + lane;
    const float* wq4 = w2T + (size_t)(jg * 5 + 4) * (Tc * COc) + iBase * COc + lane;
    const float ba = tf1b[ja], bb = tf1b[jb];
    const float bc2 = (wv < 4) ? tf1b[jc] : 0.0f;
    float hma = 0, hsa = 0, hmb = 0, hsb = 0, hmc = 0, hsc = 0;

#pragma unroll 1
    for (int chn = 0; chn < 3; ++chn) {
      const int s0 = chn * 13;
      float ya[13][5];
#pragma unroll
      for (int ds = 0; ds < 13; ++ds)
#pragma unroll
        for (int jj = 0; jj < 5; ++jj) ya[ds][jj] = 0.0f;

#pragma unroll 1
      for (int ii = 0; ii < iN; ++ii) {
        const int i = iBase + ii;
        float w0 = wq0[(size_t)ii * COc];
        float w1 = wq1[(size_t)ii * COc];
        float w2 = wq2[(size_t)ii * COc];
        float w3 = wq3[(size_t)ii * COc];
        float w4 = wq4[(size_t)ii * COc];
#pragma unroll
        for (int ds = 0; ds < 13; ++ds) {
          u32 wrd = ((const u32*)spk)[((s0 + ds) * Tc + i) * 2 + lhalf];
          float g = (float)((wrd >> lbit) & 1u);
          ya[ds][0] = fmaf(g, w0, ya[ds][0]);
          ya[ds][1] = fmaf(g, w1, ya[ds][1]);
          ya[ds][2] = fmaf(g, w2, ya[ds][2]);
          ya[ds][3] = fmaf(g, w3, ya[ds][3]);
          ya[ds][4] = fmaf(g, w4, ya[ds][4]);
        }
      }
#pragma unroll
      for (int off = 32; off >= 1; off >>= 1)
#pragma unroll
        for (int ds = 0; ds < 13; ++ds)
#pragma unroll
          for (int jj = 0; jj < 5; ++jj)
            ya[ds][jj] += __shfl_xor(ya[ds][jj], off, 64);
      if (lane == 0) {
#pragma unroll
        for (int ds = 0; ds < 13; ++ds)
#pragma unroll
          for (int jj = 0; jj < 5; ++jj)
            partials[(jg * 2 + ih) * 65 + ds * 5 + jj] = ya[ds][jj];
      }
      __syncthreads();
#pragma unroll
      for (int ds = 0; ds < 13; ++ds) {
        float y0 = partials[(jag * 2 + 0) * 65 + ds * 5 + jaj]
                 + partials[(jag * 2 + 1) * 65 + ds * 5 + jaj] + ba;
        hma = (hma * 0.2f) * ((hma > 0.5f) ? 0.0f : 1.0f) + y0;
        hsa += (hma > 0.5f) ? 1.0f : 0.0f;
        float y1 = partials[(jbg * 2 + 0) * 65 + ds * 5 + jbj]
                 + partials[(jbg * 2 + 1) * 65 + ds * 5 + jbj] + bb;
        hmb = (hmb * 0.2f) * ((hmb > 0.5f) ? 0.0f : 1.0f) + y1;
        hsb += (hmb > 0.5f) ? 1.0f : 0.0f;
        if (wv < 4) {
          float y2 = partials[(jcg * 2 + 0) * 65 + ds * 5 + jcj]
                   + partials[(jcg * 2 + 1) * 65 + ds * 5 + jcj] + bc2;
          hmc = (hmc * 0.2f) * ((hmc > 0.5f) ? 0.0f : 1.0f) + y2;
          hsc += (hmc > 0.5f) ? 1.0f : 0.0f;
        }
      }
      __syncthreads();
    }
    if (lane == 0) {
      out[b * NCc + ja] = (outS_l[ja] + hsa / (float)NSc) * 0.5f;
      out[b * NCc + jb] = (outS_l[jb] + hsb / (float)NSc) * 0.5f;
      if (wv < 4)
        out[b * NCc + jc] = (outS_l[jc] + hsc / (float)NSc) * 0.5f;
    }
  }
}

extern "C" void kernel_launch(void* const* d_in, const int* in_sizes, int n_in,
                              void* d_out, int out_size, void* d_ws, size_t ws_size,
                              hipStream_t stream) {
  const float* data = (const float*)d_in[0];
  const int*   eiS  = (const int*)d_in[1];
  const int*   eiT  = (const int*)d_in[2];
  const float* c1w  = (const float*)d_in[3];
  const float* c1b  = (const float*)d_in[4];
  const float* c2w  = (const float*)d_in[5];
  const float* c2b  = (const float*)d_in[6];
  const float* f1w  = (const float*)d_in[7];
  const float* f1b  = (const float*)d_in[8];
  const float* tf1w = (const float*)d_in[9];
  const float* tf1b = (const float*)d_in[10];
  float* out = (float*)d_out;
  int* wsI = (int*)d_ws;
  float* wsF = (float*)d_ws;

  prep_graph<<<2, 256, 0, stream>>>(eiS, eiT, wsI, wsF);
  prep_w<<<(NCc * Tc * COc + 255) / 256, 256, 0, stream>>>(f1w, wsF + WS_W1T,
                                                           tf1w, wsF + WS_W2T);
  lif_fused<<<Bc, 512, 0, stream>>>(data,
                                    wsI + WS_ROFF_S, (const int2*)(wsI + WS_EDGE_S),
                                    wsI + WS_ROFF_T, (const int2*)(wsI + WS_EDGE_T),
                                    c1w, c1b, c2w, c2b,
                                    wsF + WS_W1T, f1b, wsF + WS_W2T, tf1b,
                                    out);
}

// Round 17
// 1399.999 us; speedup vs baseline: 2.3935x; 1.0089x over previous
//
#include <hip/hip_runtime.h>

typedef unsigned int u32;
typedef unsigned long long u64;

#define Bc 256
#define Tc 325
#define NSc 39
#define COc 64
#define NCc 20
#define ESc 117
#define ETc 648

// workspace layout in 4-byte units
#define WS_ROFF_S 0        // 40 ints
#define WS_EDGE_S 64       // 117 int2
#define WS_DINV_S 304      // 39 f
#define WS_ROFF_T 352      // 326 ints
#define WS_EDGE_T 680      // 648 int2
#define WS_DINV_T 1976     // 325 f
#define WS_W1T    2304     // 49920 f  (fc1_w transposed [20][2496])
#define WS_W2T    52224    // 416000 f (tfc1_w transposed [20][20800])

// ---------------- prep: CSR (by dst, interleaved {src, nrm}) ----------------
__global__ void prep_graph(const int* __restrict__ eiS, const int* __restrict__ eiT,
                           int* __restrict__ wsI, float* __restrict__ wsF) {
  const int which = blockIdx.x;
  const int* ei = which ? eiT : eiS;
  const int nE = which ? ETc : ESc;
  const int nN = which ? Tc : NSc;
  int* roff = wsI + (which ? WS_ROFF_T : WS_ROFF_S);
  int2* edge = (int2*)(wsI + (which ? WS_EDGE_T : WS_EDGE_S));
  float* dinv = wsF + (which ? WS_DINV_T : WS_DINV_S);
  const int* src = ei;
  const int* dst = ei + nE;
  for (int n = threadIdx.x; n < nN; n += blockDim.x) {
    int deg = 0, before = 0;
    for (int e = 0; e < nE; ++e) { deg += (dst[e] == n); before += (dst[e] < n); }
    roff[n] = before;
    if (n == nN - 1) roff[nN] = before + deg;
    dinv[n] = (deg > 0) ? (1.0f / sqrtf((float)deg)) : 0.0f;
  }
  __syncthreads();
  for (int n = threadIdx.x; n < nN; n += blockDim.x) {
    int cur = roff[n];
    float dn = dinv[n];
    for (int e = 0; e < nE; ++e) {
      if (dst[e] == n) {
        edge[cur] = make_int2(src[e], __float_as_int(dinv[src[e]] * dn));
        ++cur;
      }
    }
  }
}

// ---------------- prep: transpose both fc weights ----------------
__global__ void prep_w(const float* __restrict__ w1, float* __restrict__ w1T,
                       const float* __restrict__ w2, float* __restrict__ w2T) {
  int i = blockIdx.x * 256 + threadIdx.x;
  if (i < NCc * Tc * COc) {
    int j = i / (Tc * COc);
    int p = i - j * (Tc * COc);
    w2T[i] = w2[p * NCc + j];
  }
  if (i < NCc * NSc * COc) {
    int j = i / (NSc * COc);
    int p = i - j * (NSc * COc);
    w1T[i] = w1[p * NCc + j];
  }
}

// ---------------- fused kernel: 1 batch per block, 512 threads ----------------
__global__ __launch_bounds__(512) __attribute__((amdgpu_waves_per_eu(2, 2)))
void lif_fused(const float* __restrict__ data,
               const int* __restrict__ roffSg, const int2* __restrict__ edgeSg,
               const int* __restrict__ roffTg, const int2* __restrict__ edgeTg,
               const float* __restrict__ c1w, const float* __restrict__ c1b,
               const float* __restrict__ c2w, const float* __restrict__ c2b,
               const float* __restrict__ w1T, const float* __restrict__ f1b,
               const float* __restrict__ w2T, const float* __restrict__ tf1b,
               float* __restrict__ out)
{
  __shared__ u64 spk[NSc * Tc];                  // 101400 B: A=[t][39], B=[s][325]
  __shared__ __align__(16) float fAB[13000];     // A: [16][39][16] / B: 2 planes [325][20]
  __shared__ float partials[520];
  __shared__ float outS_l[NCc];
  __shared__ int roffS[NSc + 1];
  __shared__ int2 edgeS[ESc];
  __shared__ int roffT[Tc + 1];
  __shared__ int2 edgeT[ETc];

  const int tid = threadIdx.x;
  const int lane = tid & 63;
  const int wv = tid >> 6;             // 0..7
  const int b = blockIdx.x;
  const int lhalf = lane >> 5;
  const int lbit = lane & 31;
  const float* dbase = data + (size_t)b * (2 * NSc * 2 * Tc);

  for (int i = tid; i < NSc + 1; i += 512) roffS[i] = roffSg[i];
  for (int i = tid; i < ESc; i += 512) edgeS[i] = edgeSg[i];
  for (int i = tid; i < Tc + 1; i += 512) roffT[i] = roffTg[i];
  for (int i = tid; i < ETc; i += 512) edgeT[i] = edgeTg[i];

  // common decomposition for fc GEMM + owned LIF outputs
  const int jg = wv >> 1, ih = wv & 1;
  const int ja = wv, jb = wv + 8, jc = wv + 16;
  const int jag = ja / 5, jaj = ja % 5;
  const int jbg = jb / 5, jbj = jb % 5;
  const int jcg = jc / 5, jcj = jc % 5;

  // ============ Phase A: spatial, per 13-t chunk: {stage, hops, conv+LIF, fc GEMM, h-LIF} ============
  {
    const float bcv = c1b[lane];
    float cm[5] = {0, 0, 0, 0, 0};
    const int iBase = ih * 20, iN = ih ? 19 : 20;
    const float* wq0 = w1T + (jg * 5 + 0) * (NSc * COc) + iBase * COc + lane;
    const float* wq1 = w1T + (jg * 5 + 1) * (NSc * COc) + iBase * COc + lane;
    const float* wq2 = w1T + (jg * 5 + 2) * (NSc * COc) + iBase * COc + lane;
    const float* wq3 = w1T + (jg * 5 + 3) * (NSc * COc) + iBase * COc + lane;
    const float* wq4 = w1T + (jg * 5 + 4) * (NSc * COc) + iBase * COc + lane;
    const float ba = f1b[ja], bb = f1b[jb];
    const float bc2 = (wv < 4) ? f1b[jc] : 0.0f;
    float hma = 0, hsa = 0, hmb = 0, hsb = 0, hmc = 0, hsc = 0;
    __syncthreads();

#pragma unroll 1
    for (int ch = 0; ch < 25; ++ch) {
      const int t0 = ch * 13;
      // stage x: fA[c][n][dt16]
#pragma unroll
      for (int it = 0; it < 5; ++it) {
        int idx = tid + it * 512;
        if (idx < 2496) {
          int n = idx >> 6, c = (idx >> 4) & 3, dt = idx & 15;
          float v = 0.0f;
          if (dt < 13) v = dbase[(n + (c >> 1) * NSc) * 650 + (c & 1) * 325 + t0 + dt];
          fAB[c * 624 + n * 16 + dt] = v;
        }
      }
      __syncthreads();
      // 3 hops
#pragma unroll
      for (int k = 1; k <= 3; ++k) {
#pragma unroll
        for (int it = 0; it < 5; ++it) {
          int idx = tid + it * 512;
          if (idx < 2496) {
            int n = idx >> 6, c = (idx >> 4) & 3, dt = idx & 15;
            float v = 0.0f;
            for (int e = roffS[n]; e < roffS[n + 1]; ++e) {
              int2 ed = edgeS[e];
              v = fmaf(__int_as_float(ed.y), fAB[((k - 1) * 4 + c) * 624 + ed.x * 16 + dt], v);
            }
            fAB[(k * 4 + c) * 624 + n * 16 + dt] = v;
          }
        }
        __syncthreads();
      }
      // conv + LIF + ballot -> spk[t][i]
      {
        float wcr[16];
#pragma unroll
        for (int r = 0; r < 16; ++r) wcr[r] = c1w[r * COc + lane];
#pragma unroll
        for (int q = 0; q < 5; ++q) {
          int i = wv + 8 * q;
          if (i < NSc) {
            float za[13];
#pragma unroll
            for (int dt = 0; dt < 13; ++dt) za[dt] = bcv;
#pragma unroll
            for (int r = 0; r < 16; ++r) {
              const float* fp = &fAB[r * 624 + i * 16];
              float w = wcr[r];
              float4 a0 = *(const float4*)fp;
              float4 a1 = *(const float4*)(fp + 4);
              float4 a2 = *(const float4*)(fp + 8);
              float a3 = fp[12];
              za[0] = fmaf(a0.x, w, za[0]);   za[1] = fmaf(a0.y, w, za[1]);
              za[2] = fmaf(a0.z, w, za[2]);   za[3] = fmaf(a0.w, w, za[3]);
              za[4] = fmaf(a1.x, w, za[4]);   za[5] = fmaf(a1.y, w, za[5]);
              za[6] = fmaf(a1.z, w, za[6]);   za[7] = fmaf(a1.w, w, za[7]);
              za[8] = fmaf(a2.x, w, za[8]);   za[9] = fmaf(a2.y, w, za[9]);
              za[10] = fmaf(a2.z, w, za[10]); za[11] = fmaf(a2.w, w, za[11]);
              za[12] = fmaf(a3, w, za[12]);
            }
#pragma unroll
            for (int dt = 0; dt < 13; ++dt) {
              float old = cm[q];
              float m = (old * 0.2f) * ((old > 0.5f) ? 0.0f : 1.0f) + za[dt];
              cm[q] = m;
              u64 wd = __ballot(m > 0.5f);
              if (lane == 0) spk[(t0 + dt) * NSc + i] = wd;
            }
          }
        }
      }
      __syncthreads();
      // fc GEMM over chunk (software-pipelined weight prefetch)
      float ya[13][5];
#pragma unroll
      for (int ds = 0; ds < 13; ++ds)
#pragma unroll
        for (int jj = 0; jj < 5; ++jj) ya[ds][jj] = 0.0f;
      {
        float w0 = wq0[0], w1 = wq1[0], w2 = wq2[0], w3 = wq3[0], w4 = wq4[0];
#pragma unroll 1
        for (int ii = 0; ii < iN; ++ii) {
          const int i = iBase + ii;
          const int iin = (ii + 1 < iN) ? ii + 1 : ii;
          float nw0 = wq0[iin * COc];
          float nw1 = wq1[iin * COc];
          float nw2 = wq2[iin * COc];
          float nw3 = wq3[iin * COc];
          float nw4 = wq4[iin * COc];
#pragma unroll
          for (int ds = 0; ds < 13; ++ds) {
            u32 wrd = ((const u32*)spk)[((t0 + ds) * NSc + i) * 2 + lhalf];
            float g = (float)((wrd >> lbit) & 1u);
            ya[ds][0] = fmaf(g, w0, ya[ds][0]);
            ya[ds][1] = fmaf(g, w1, ya[ds][1]);
            ya[ds][2] = fmaf(g, w2, ya[ds][2]);
            ya[ds][3] = fmaf(g, w3, ya[ds][3]);
            ya[ds][4] = fmaf(g, w4, ya[ds][4]);
          }
          w0 = nw0; w1 = nw1; w2 = nw2; w3 = nw3; w4 = nw4;
        }
      }
#pragma unroll
      for (int off = 32; off >= 1; off >>= 1)
#pragma unroll
        for (int ds = 0; ds < 13; ++ds)
#pragma unroll
          for (int jj = 0; jj < 5; ++jj)
            ya[ds][jj] += __shfl_xor(ya[ds][jj], off, 64);
      if (lane == 0) {
#pragma unroll
        for (int ds = 0; ds < 13; ++ds)
#pragma unroll
          for (int jj = 0; jj < 5; ++jj)
            partials[(jg * 2 + ih) * 65 + ds * 5 + jj] = ya[ds][jj];
      }
      __syncthreads();
      // h-LIF for owned outputs
#pragma unroll
      for (int ds = 0; ds < 13; ++ds) {
        float y0 = partials[(jag * 2 + 0) * 65 + ds * 5 + jaj]
                 + partials[(jag * 2 + 1) * 65 + ds * 5 + jaj] + ba;
        hma = (hma * 0.2f) * ((hma > 0.5f) ? 0.0f : 1.0f) + y0;
        hsa += (hma > 0.5f) ? 1.0f : 0.0f;
        float y1 = partials[(jbg * 2 + 0) * 65 + ds * 5 + jbj]
                 + partials[(jbg * 2 + 1) * 65 + ds * 5 + jbj] + bb;
        hmb = (hmb * 0.2f) * ((hmb > 0.5f) ? 0.0f : 1.0f) + y1;
        hsb += (hmb > 0.5f) ? 1.0f : 0.0f;
        if (wv < 4) {
          float y2 = partials[(jcg * 2 + 0) * 65 + ds * 5 + jcj]
                   + partials[(jcg * 2 + 1) * 65 + ds * 5 + jcj] + bc2;
          hmc = (hmc * 0.2f) * ((hmc > 0.5f) ? 0.0f : 1.0f) + y2;
          hsc += (hmc > 0.5f) ? 1.0f : 0.0f;
        }
      }
      __syncthreads();
    }
    if (lane == 0) {
      outS_l[ja] = hsa / (float)Tc;
      outS_l[jb] = hsb / (float)Tc;
      if (wv < 4) outS_l[jc] = hsc / (float)Tc;
    }
  }
  __syncthreads();

  // ============ Phase B1: temporal conv chain, 2 s-steps per barrier group ============
  {
    float wc[16];
#pragma unroll
    for (int r = 0; r < 16; ++r) wc[r] = c2w[r * COc + lane];
    const float bcv = c2b[lane];
    float tm[41];
#pragma unroll
    for (int q = 0; q < 41; ++q) tm[q] = 0.0f;

#pragma unroll 1
    for (int pr = 0; pr < 20; ++pr) {
      const int sA = pr * 2;
      const int pN = (sA + 1 < NSc) ? 2 : 1;
      const int items = pN * 1300;
      // stage pN planes: fAB[p*6500 + t*20 + c]
#pragma unroll
      for (int it = 0; it < 6; ++it) {
        int idx = tid + it * 512;
        if (idx < items) {
          int p = (idx >= 1300) ? 1 : 0;
          int q2 = idx - p * 1300;
          int c = q2 / 325, t = q2 - c * 325;
          fAB[p * 6500 + t * 20 + c] =
              dbase[((sA + p) + (c >> 1) * NSc) * 650 + (c & 1) * 325 + t];
        }
      }
      __syncthreads();
      // 3 hops over both planes
#pragma unroll
      for (int k = 1; k <= 3; ++k) {
#pragma unroll
        for (int it = 0; it < 6; ++it) {
          int idx = tid + it * 512;
          if (idx < items) {
            int p = (idx >= 1300) ? 1 : 0;
            int q2 = idx - p * 1300;
            int t = q2 >> 2, c = q2 & 3;
            float v = 0.0f;
            for (int e = roffT[t]; e < roffT[t + 1]; ++e) {
              int2 ed = edgeT[e];
              v = fmaf(__int_as_float(ed.y), fAB[p * 6500 + ed.x * 20 + (k - 1) * 4 + c], v);
            }
            fAB[p * 6500 + t * 20 + k * 4 + c] = v;
          }
        }
        __syncthreads();
      }
      // conv + LIF (sequential over the pair) + ballot
#pragma unroll
      for (int q = 0; q < 41; ++q) {
        int i = wv + 8 * q;
        if (i < Tc) {
          float m = tm[q];
#pragma unroll
          for (int p = 0; p < 2; ++p) {
            if (p < pN) {
              const float4* f4 = (const float4*)&fAB[p * 6500 + i * 20];
              float4 f0 = f4[0], f1 = f4[1], f2 = f4[2], f3 = f4[3];
              float acc = bcv;
              acc = fmaf(f0.x, wc[0], acc);  acc = fmaf(f0.y, wc[1], acc);
              acc = fmaf(f0.z, wc[2], acc);  acc = fmaf(f0.w, wc[3], acc);
              acc = fmaf(f1.x, wc[4], acc);  acc = fmaf(f1.y, wc[5], acc);
              acc = fmaf(f1.z, wc[6], acc);  acc = fmaf(f1.w, wc[7], acc);
              acc = fmaf(f2.x, wc[8], acc);  acc = fmaf(f2.y, wc[9], acc);
              acc = fmaf(f2.z, wc[10], acc); acc = fmaf(f2.w, wc[11], acc);
              acc = fmaf(f3.x, wc[12], acc); acc = fmaf(f3.y, wc[13], acc);
              acc = fmaf(f3.z, wc[14], acc); acc = fmaf(f3.w, wc[15], acc);
              m = (m * 0.2f) * ((m > 0.5f) ? 0.0f : 1.0f) + acc;
              u64 wd = __ballot(m > 0.5f);
              if (lane == 0) spk[(sA + p) * Tc + i] = wd;
            }
          }
          tm[q] = m;
        }
      }
      __syncthreads();
    }
  }

  // ============ Phase B2: temporal fc binary GEMM (prefetched) + h-LIF + combine ============
  {
    const int iBase = ih * 163, iN = ih ? 162 : 163;
    const float* wq0 = w2T + (size_t)(jg * 5 + 0) * (Tc * COc) + iBase * COc + lane;
    const float* wq1 = w2T + (size_t)(jg * 5 + 1) * (Tc * COc) + iBase * COc + lane;
    const float* wq2 = w2T + (size_t)(jg * 5 + 2) * (Tc * COc) + iBase * COc + lane;
    const float* wq3 = w2T + (size_t)(jg * 5 + 3) * (Tc * COc) + iBase * COc + lane;
    const float* wq4 = w2T + (size_t)(jg * 5 + 4) * (Tc * COc) + iBase * COc + lane;
    const float ba = tf1b[ja], bb = tf1b[jb];
    const float bc2 = (wv < 4) ? tf1b[jc] : 0.0f;
    float hma = 0, hsa = 0, hmb = 0, hsb = 0, hmc = 0, hsc = 0;

#pragma unroll 1
    for (int chn = 0; chn < 3; ++chn) {
      const int s0 = chn * 13;
      float ya[13][5];
#pragma unroll
      for (int ds = 0; ds < 13; ++ds)
#pragma unroll
        for (int jj = 0; jj < 5; ++jj) ya[ds][jj] = 0.0f;

      {
        float w0 = wq0[0], w1 = wq1[0], w2 = wq2[0], w3 = wq3[0], w4 = wq4[0];
#pragma unroll 1
        for (int ii = 0; ii < iN; ++ii) {
          const int i = iBase + ii;
          const int iin = (ii + 1 < iN) ? ii + 1 : ii;
          float nw0 = wq0[(size_t)iin * COc];
          float nw1 = wq1[(size_t)iin * COc];
          float nw2 = wq2[(size_t)iin * COc];
          float nw3 = wq3[(size_t)iin * COc];
          float nw4 = wq4[(size_t)iin * COc];
#pragma unroll
          for (int ds = 0; ds < 13; ++ds) {
            u32 wrd = ((const u32*)spk)[((s0 + ds) * Tc + i) * 2 + lhalf];
            float g = (float)((wrd >> lbit) & 1u);
            ya[ds][0] = fmaf(g, w0, ya[ds][0]);
            ya[ds][1] = fmaf(g, w1, ya[ds][1]);
            ya[ds][2] = fmaf(g, w2, ya[ds][2]);
            ya[ds][3] = fmaf(g, w3, ya[ds][3]);
            ya[ds][4] = fmaf(g, w4, ya[ds][4]);
          }
          w0 = nw0; w1 = nw1; w2 = nw2; w3 = nw3; w4 = nw4;
        }
      }
#pragma unroll
      for (int off = 32; off >= 1; off >>= 1)
#pragma unroll
        for (int ds = 0; ds < 13; ++ds)
#pragma unroll
          for (int jj = 0; jj < 5; ++jj)
            ya[ds][jj] += __shfl_xor(ya[ds][jj], off, 64);
      if (lane == 0) {
#pragma unroll
        for (int ds = 0; ds < 13; ++ds)
#pragma unroll
          for (int jj = 0; jj < 5; ++jj)
            partials[(jg * 2 + ih) * 65 + ds * 5 + jj] = ya[ds][jj];
      }
      __syncthreads();
#pragma unroll
      for (int ds = 0; ds < 13; ++ds) {
        float y0 = partials[(jag * 2 + 0) * 65 + ds * 5 + jaj]
                 + partials[(jag * 2 + 1) * 65 + ds * 5 + jaj] + ba;
        hma = (hma * 0.2f) * ((hma > 0.5f) ? 0.0f : 1.0f) + y0;
        hsa += (hma > 0.5f) ? 1.0f : 0.0f;
        float y1 = partials[(jbg * 2 + 0) * 65 + ds * 5 + jbj]
                 + partials[(jbg * 2 + 1) * 65 + ds * 5 + jbj] + bb;
        hmb = (hmb * 0.2f) * ((hmb > 0.5f) ? 0.0f : 1.0f) + y1;
        hsb += (hmb > 0.5f) ? 1.0f : 0.0f;
        if (wv < 4) {
          float y2 = partials[(jcg * 2 + 0) * 65 + ds * 5 + jcj]
                   + partials[(jcg * 2 + 1) * 65 + ds * 5 + jcj] + bc2;
          hmc = (hmc * 0.2f) * ((hmc > 0.5f) ? 0.0f : 1.0f) + y2;
          hsc += (hmc > 0.5f) ? 1.0f : 0.0f;
        }
      }
      __syncthreads();
    }
    if (lane == 0) {
      out[b * NCc + ja] = (outS_l[ja] + hsa / (float)NSc) * 0.5f;
      out[b * NCc + jb] = (outS_l[jb] + hsb / (float)NSc) * 0.5f;
      if (wv < 4)
        out[b * NCc + jc] = (outS_l[jc] + hsc / (float)NSc) * 0.5f;
    }
  }
}

extern "C" void kernel_launch(void* const* d_in, const int* in_sizes, int n_in,
                              void* d_out, int out_size, void* d_ws, size_t ws_size,
                              hipStream_t stream) {
  const float* data = (const float*)d_in[0];
  const int*   eiS  = (const int*)d_in[1];
  const int*   eiT  = (const int*)d_in[2];
  const float* c1w  = (const float*)d_in[3];
  const float* c1b  = (const float*)d_in[4];
  const float* c2w  = (const float*)d_in[5];
  const float* c2b  = (const float*)d_in[6];
  const float* f1w  = (const float*)d_in[7];
  const float* f1b  = (const float*)d_in[8];
  const float* tf1w = (const float*)d_in[9];
  const float* tf1b = (const float*)d_in[10];
  float* out = (float*)d_out;
  int* wsI = (int*)d_ws;
  float* wsF = (float*)d_ws;

  prep_graph<<<2, 256, 0, stream>>>(eiS, eiT, wsI, wsF);
  prep_w<<<(NCc * Tc * COc + 255) / 256, 256, 0, stream>>>(f1w, wsF + WS_W1T,
                                                           tf1w, wsF + WS_W2T);
  lif_fused<<<Bc, 512, 0, stream>>>(data,
                                    wsI + WS_ROFF_S, (const int2*)(wsI + WS_EDGE_S),
                                    wsI + WS_ROFF_T, (const int2*)(wsI + WS_EDGE_T),
                                    c1w, c1b, c2w, c2b,
                                    wsF + WS_W1T, f1b, wsF + WS_W2T, tf1b,
                                    out);
}

// Round 18
// 1334.419 us; speedup vs baseline: 2.5112x; 1.0491x over previous
//
#include <hip/hip_runtime.h>

typedef unsigned int u32;
typedef unsigned long long u64;
typedef short bf16x8 __attribute__((ext_vector_type(8)));
typedef float f32x4 __attribute__((ext_vector_type(4)));

#define Bc 256
#define Tc 325
#define NSc 39
#define COc 64
#define NCc 20
#define ESc 117
#define ETc 648

// workspace layout in 4-byte units
#define WS_ROFF_S 0        // 40 ints
#define WS_EDGE_S 64       // 117 int2
#define WS_DINV_S 304      // 39 f
#define WS_ROFF_T 352      // 326 ints
#define WS_EDGE_T 680      // 648 int2
#define WS_DINV_T 1976     // 325 f
#define WS_W1T    2304     // 49920 f  (fc1_w transposed [20][2496])
#define WS_W2T    52224    // 416000 f (unused by kernel now; kept for prep simplicity)

// ---------------- prep: CSR (by dst, interleaved {src, nrm}) ----------------
__global__ void prep_graph(const int* __restrict__ eiS, const int* __restrict__ eiT,
                           int* __restrict__ wsI, float* __restrict__ wsF) {
  const int which = blockIdx.x;
  const int* ei = which ? eiT : eiS;
  const int nE = which ? ETc : ESc;
  const int nN = which ? Tc : NSc;
  int* roff = wsI + (which ? WS_ROFF_T : WS_ROFF_S);
  int2* edge = (int2*)(wsI + (which ? WS_EDGE_T : WS_EDGE_S));
  float* dinv = wsF + (which ? WS_DINV_T : WS_DINV_S);
  const int* src = ei;
  const int* dst = ei + nE;
  for (int n = threadIdx.x; n < nN; n += blockDim.x) {
    int deg = 0, before = 0;
    for (int e = 0; e < nE; ++e) { deg += (dst[e] == n); before += (dst[e] < n); }
    roff[n] = before;
    if (n == nN - 1) roff[nN] = before + deg;
    dinv[n] = (deg > 0) ? (1.0f / sqrtf((float)deg)) : 0.0f;
  }
  __syncthreads();
  for (int n = threadIdx.x; n < nN; n += blockDim.x) {
    int cur = roff[n];
    float dn = dinv[n];
    for (int e = 0; e < nE; ++e) {
      if (dst[e] == n) {
        edge[cur] = make_int2(src[e], __float_as_int(dinv[src[e]] * dn));
        ++cur;
      }
    }
  }
}

// ---------------- prep: transpose fc1 weights ----------------
__global__ void prep_w(const float* __restrict__ w1, float* __restrict__ w1T,
                       const float* __restrict__ w2, float* __restrict__ w2T) {
  int i = blockIdx.x * 256 + threadIdx.x;
  if (i < NCc * Tc * COc) {
    int j = i / (Tc * COc);
    int p = i - j * (Tc * COc);
    w2T[i] = w2[p * NCc + j];
  }
  if (i < NCc * NSc * COc) {
    int j = i / (NSc * COc);
    int p = i - j * (NSc * COc);
    w1T[i] = w1[p * NCc + j];
  }
}

// ---------------- fused kernel: 1 batch per block, 512 threads ----------------
__global__ __launch_bounds__(512) __attribute__((amdgpu_waves_per_eu(2, 2)))
void lif_fused(const float* __restrict__ data,
               const int* __restrict__ roffSg, const int2* __restrict__ edgeSg,
               const int* __restrict__ roffTg, const int2* __restrict__ edgeTg,
               const float* __restrict__ c1w, const float* __restrict__ c1b,
               const float* __restrict__ c2w, const float* __restrict__ c2b,
               const float* __restrict__ w1T, const float* __restrict__ f1b,
               const float* __restrict__ tf1w, const float* __restrict__ tf1b,
               float* __restrict__ out)
{
  __shared__ u64 spk[NSc * Tc];                  // 101400 B: A=[t][39], B=[s][325]
  __shared__ __align__(16) float fAB[13000];     // A: [16][39][16] / B: 2 planes / B2: partials
  __shared__ float partials[520];
  __shared__ float outS_l[NCc];
  __shared__ int roffS[NSc + 1];
  __shared__ int2 edgeS[ESc];
  __shared__ int roffT[Tc + 1];
  __shared__ int2 edgeT[ETc];

  const int tid = threadIdx.x;
  const int lane = tid & 63;
  const int wv = tid >> 6;             // 0..7
  const int b = blockIdx.x;
  const int lhalf = lane >> 5;
  const int lbit = lane & 31;
  const float* dbase = data + (size_t)b * (2 * NSc * 2 * Tc);

  for (int i = tid; i < NSc + 1; i += 512) roffS[i] = roffSg[i];
  for (int i = tid; i < ESc; i += 512) edgeS[i] = edgeSg[i];
  for (int i = tid; i < Tc + 1; i += 512) roffT[i] = roffTg[i];
  for (int i = tid; i < ETc; i += 512) edgeT[i] = edgeTg[i];

  // common decomposition for fc GEMM + owned LIF outputs
  const int jg = wv >> 1, ih = wv & 1;
  const int ja = wv, jb = wv + 8, jc = wv + 16;
  const int jag = ja / 5, jaj = ja % 5;
  const int jbg = jb / 5, jbj = jb % 5;
  const int jcg = jc / 5, jcj = jc % 5;

  // ============ Phase A: spatial, per 13-t chunk ============
  {
    const float bcv = c1b[lane];
    float cm[5] = {0, 0, 0, 0, 0};
    const int iBase = ih * 20, iN = ih ? 19 : 20;
    const float* wq0 = w1T + (jg * 5 + 0) * (NSc * COc) + iBase * COc + lane;
    const float* wq1 = w1T + (jg * 5 + 1) * (NSc * COc) + iBase * COc + lane;
    const float* wq2 = w1T + (jg * 5 + 2) * (NSc * COc) + iBase * COc + lane;
    const float* wq3 = w1T + (jg * 5 + 3) * (NSc * COc) + iBase * COc + lane;
    const float* wq4 = w1T + (jg * 5 + 4) * (NSc * COc) + iBase * COc + lane;
    const float ba = f1b[ja], bb = f1b[jb];
    const float bc2 = (wv < 4) ? f1b[jc] : 0.0f;
    float hma = 0, hsa = 0, hmb = 0, hsb = 0, hmc = 0, hsc = 0;
    __syncthreads();

#pragma unroll 1
    for (int ch = 0; ch < 25; ++ch) {
      const int t0 = ch * 13;
#pragma unroll
      for (int it = 0; it < 5; ++it) {
        int idx = tid + it * 512;
        if (idx < 2496) {
          int n = idx >> 6, c = (idx >> 4) & 3, dt = idx & 15;
          float v = 0.0f;
          if (dt < 13) v = dbase[(n + (c >> 1) * NSc) * 650 + (c & 1) * 325 + t0 + dt];
          fAB[c * 624 + n * 16 + dt] = v;
        }
      }
      __syncthreads();
#pragma unroll
      for (int k = 1; k <= 3; ++k) {
#pragma unroll
        for (int it = 0; it < 5; ++it) {
          int idx = tid + it * 512;
          if (idx < 2496) {
            int n = idx >> 6, c = (idx >> 4) & 3, dt = idx & 15;
            float v = 0.0f;
            for (int e = roffS[n]; e < roffS[n + 1]; ++e) {
              int2 ed = edgeS[e];
              v = fmaf(__int_as_float(ed.y), fAB[((k - 1) * 4 + c) * 624 + ed.x * 16 + dt], v);
            }
            fAB[(k * 4 + c) * 624 + n * 16 + dt] = v;
          }
        }
        __syncthreads();
      }
      {
        float wcr[16];
#pragma unroll
        for (int r = 0; r < 16; ++r) wcr[r] = c1w[r * COc + lane];
#pragma unroll
        for (int q = 0; q < 5; ++q) {
          int i = wv + 8 * q;
          if (i < NSc) {
            float za[13];
#pragma unroll
            for (int dt = 0; dt < 13; ++dt) za[dt] = bcv;
#pragma unroll
            for (int r = 0; r < 16; ++r) {
              const float* fp = &fAB[r * 624 + i * 16];
              float w = wcr[r];
              float4 a0 = *(const float4*)fp;
              float4 a1 = *(const float4*)(fp + 4);
              float4 a2 = *(const float4*)(fp + 8);
              float a3 = fp[12];
              za[0] = fmaf(a0.x, w, za[0]);   za[1] = fmaf(a0.y, w, za[1]);
              za[2] = fmaf(a0.z, w, za[2]);   za[3] = fmaf(a0.w, w, za[3]);
              za[4] = fmaf(a1.x, w, za[4]);   za[5] = fmaf(a1.y, w, za[5]);
              za[6] = fmaf(a1.z, w, za[6]);   za[7] = fmaf(a1.w, w, za[7]);
              za[8] = fmaf(a2.x, w, za[8]);   za[9] = fmaf(a2.y, w, za[9]);
              za[10] = fmaf(a2.z, w, za[10]); za[11] = fmaf(a2.w, w, za[11]);
              za[12] = fmaf(a3, w, za[12]);
            }
#pragma unroll
            for (int dt = 0; dt < 13; ++dt) {
              float old = cm[q];
              float m = (old * 0.2f) * ((old > 0.5f) ? 0.0f : 1.0f) + za[dt];
              cm[q] = m;
              u64 wd = __ballot(m > 0.5f);
              if (lane == 0) spk[(t0 + dt) * NSc + i] = wd;
            }
          }
        }
      }
      __syncthreads();
      // fc GEMM over chunk (software-pipelined weight prefetch)
      float ya[13][5];
#pragma unroll
      for (int ds = 0; ds < 13; ++ds)
#pragma unroll
        for (int jj = 0; jj < 5; ++jj) ya[ds][jj] = 0.0f;
      {
        float w0 = wq0[0], w1 = wq1[0], w2 = wq2[0], w3 = wq3[0], w4 = wq4[0];
#pragma unroll 1
        for (int ii = 0; ii < iN; ++ii) {
          const int i = iBase + ii;
          const int iin = (ii + 1 < iN) ? ii + 1 : ii;
          float nw0 = wq0[iin * COc];
          float nw1 = wq1[iin * COc];
          float nw2 = wq2[iin * COc];
          float nw3 = wq3[iin * COc];
          float nw4 = wq4[iin * COc];
#pragma unroll
          for (int ds = 0; ds < 13; ++ds) {
            u32 wrd = ((const u32*)spk)[((t0 + ds) * NSc + i) * 2 + lhalf];
            float g = (float)((wrd >> lbit) & 1u);
            ya[ds][0] = fmaf(g, w0, ya[ds][0]);
            ya[ds][1] = fmaf(g, w1, ya[ds][1]);
            ya[ds][2] = fmaf(g, w2, ya[ds][2]);
            ya[ds][3] = fmaf(g, w3, ya[ds][3]);
            ya[ds][4] = fmaf(g, w4, ya[ds][4]);
          }
          w0 = nw0; w1 = nw1; w2 = nw2; w3 = nw3; w4 = nw4;
        }
      }
#pragma unroll
      for (int off = 32; off >= 1; off >>= 1)
#pragma unroll
        for (int ds = 0; ds < 13; ++ds)
#pragma unroll
          for (int jj = 0; jj < 5; ++jj)
            ya[ds][jj] += __shfl_xor(ya[ds][jj], off, 64);
      if (lane == 0) {
#pragma unroll
        for (int ds = 0; ds < 13; ++ds)
#pragma unroll
          for (int jj = 0; jj < 5; ++jj)
            partials[(jg * 2 + ih) * 65 + ds * 5 + jj] = ya[ds][jj];
      }
      __syncthreads();
#pragma unroll
      for (int ds = 0; ds < 13; ++ds) {
        float y0 = partials[(jag * 2 + 0) * 65 + ds * 5 + jaj]
                 + partials[(jag * 2 + 1) * 65 + ds * 5 + jaj] + ba;
        hma = (hma * 0.2f) * ((hma > 0.5f) ? 0.0f : 1.0f) + y0;
        hsa += (hma > 0.5f) ? 1.0f : 0.0f;
        float y1 = partials[(jbg * 2 + 0) * 65 + ds * 5 + jbj]
                 + partials[(jbg * 2 + 1) * 65 + ds * 5 + jbj] + bb;
        hmb = (hmb * 0.2f) * ((hmb > 0.5f) ? 0.0f : 1.0f) + y1;
        hsb += (hmb > 0.5f) ? 1.0f : 0.0f;
        if (wv < 4) {
          float y2 = partials[(jcg * 2 + 0) * 65 + ds * 5 + jcj]
                   + partials[(jcg * 2 + 1) * 65 + ds * 5 + jcj] + bc2;
          hmc = (hmc * 0.2f) * ((hmc > 0.5f) ? 0.0f : 1.0f) + y2;
          hsc += (hmc > 0.5f) ? 1.0f : 0.0f;
        }
      }
      __syncthreads();
    }
    if (lane == 0) {
      outS_l[ja] = hsa / (float)Tc;
      outS_l[jb] = hsb / (float)Tc;
      if (wv < 4) outS_l[jc] = hsc / (float)Tc;
    }
  }
  __syncthreads();

  // ============ Phase B1: temporal conv chain, 2 s-steps per barrier group ============
  {
    float wc[16];
#pragma unroll
    for (int r = 0; r < 16; ++r) wc[r] = c2w[r * COc + lane];
    const float bcv = c2b[lane];
    float tm[41];
#pragma unroll
    for (int q = 0; q < 41; ++q) tm[q] = 0.0f;

#pragma unroll 1
    for (int pr = 0; pr < 20; ++pr) {
      const int sA = pr * 2;
      const int pN = (sA + 1 < NSc) ? 2 : 1;
      const int items = pN * 1300;
#pragma unroll
      for (int it = 0; it < 6; ++it) {
        int idx = tid + it * 512;
        if (idx < items) {
          int p = (idx >= 1300) ? 1 : 0;
          int q2 = idx - p * 1300;
          int c = q2 / 325, t = q2 - c * 325;
          fAB[p * 6500 + t * 20 + c] =
              dbase[((sA + p) + (c >> 1) * NSc) * 650 + (c & 1) * 325 + t];
        }
      }
      __syncthreads();
#pragma unroll
      for (int k = 1; k <= 3; ++k) {
#pragma unroll
        for (int it = 0; it < 6; ++it) {
          int idx = tid + it * 512;
          if (idx < items) {
            int p = (idx >= 1300) ? 1 : 0;
            int q2 = idx - p * 1300;
            int t = q2 >> 2, c = q2 & 3;
            float v = 0.0f;
            for (int e = roffT[t]; e < roffT[t + 1]; ++e) {
              int2 ed = edgeT[e];
              v = fmaf(__int_as_float(ed.y), fAB[p * 6500 + ed.x * 20 + (k - 1) * 4 + c], v);
            }
            fAB[p * 6500 + t * 20 + k * 4 + c] = v;
          }
        }
        __syncthreads();
      }
#pragma unroll
      for (int q = 0; q < 41; ++q) {
        int i = wv + 8 * q;
        if (i < Tc) {
          float m = tm[q];
#pragma unroll
          for (int p = 0; p < 2; ++p) {
            if (p < pN) {
              const float4* f4 = (const float4*)&fAB[p * 6500 + i * 20];
              float4 f0 = f4[0], f1 = f4[1], f2 = f4[2], f3 = f4[3];
              float acc = bcv;
              acc = fmaf(f0.x, wc[0], acc);  acc = fmaf(f0.y, wc[1], acc);
              acc = fmaf(f0.z, wc[2], acc);  acc = fmaf(f0.w, wc[3], acc);
              acc = fmaf(f1.x, wc[4], acc);  acc = fmaf(f1.y, wc[5], acc);
              acc = fmaf(f1.z, wc[6], acc);  acc = fmaf(f1.w, wc[7], acc);
              acc = fmaf(f2.x, wc[8], acc);  acc = fmaf(f2.y, wc[9], acc);
              acc = fmaf(f2.z, wc[10], acc); acc = fmaf(f2.w, wc[11], acc);
              acc = fmaf(f3.x, wc[12], acc); acc = fmaf(f3.y, wc[13], acc);
              acc = fmaf(f3.z, wc[14], acc); acc = fmaf(f3.w, wc[15], acc);
              m = (m * 0.2f) * ((m > 0.5f) ? 0.0f : 1.0f) + acc;
              u64 wd = __ballot(m > 0.5f);
              if (lane == 0) spk[(sA + p) * Tc + i] = wd;
            }
          }
          tm[q] = m;
        }
      }
      __syncthreads();
    }
  }

  // ============ Phase B2: temporal fc via MFMA (bf16 hi/mid/lo split) + h-LIF + combine ============
  {
    const u32* spk32 = (const u32*)spk;
    float* part = fAB;                 // reuse: [2 nt][4 kq][3 mt][16 row][16 col] = 6144 f
    const int kqi = wv & 3;
    const int nt = wv >> 2;
    const int col = nt * 16 + (lane & 15);
    const int lgrp = lane >> 4;        // 0..3: k-subgroup
    const int srow = lane & 15;        // A row / C col lane index
    const int kt0 = (kqi < 2) ? kqi * 163 : 326 + (kqi - 2) * 162;
    const int ktN = (kqi < 2) ? 163 : 162;

    f32x4 c0 = {0, 0, 0, 0}, c1 = {0, 0, 0, 0}, c2 = {0, 0, 0, 0};

#pragma unroll 1
    for (int kk = 0; kk < ktN; ++kk) {
      const int kt = kt0 + kk;
      const int kbase = kt * 32 + lgrp * 8;
      // weights: W[k][col] from tf1w [20800][20]; split into hi/mid/lo bf16 (exact to ~2^-24)
      bf16x8 Bhi, Bmid, Blo;
#pragma unroll
      for (int j = 0; j < 8; ++j) {
        float w = (col < NCc) ? tf1w[(kbase + j) * NCc + col] : 0.0f;
        u32 bw = __float_as_uint(w);
        u32 hbits = bw & 0xFFFF0000u;
        float r1 = w - __uint_as_float(hbits);
        u32 mbits = __float_as_uint(r1) & 0xFFFF0000u;
        float r2 = r1 - __uint_as_float(mbits);
        Bhi[j] = (short)(hbits >> 16);
        Bmid[j] = (short)(mbits >> 16);
        Blo[j] = (short)(__float_as_uint(r2) >> 16);
      }
      const int widx = (kt >> 1);
      const int wsel = (kt & 1);
      const int shft = lgrp * 8;
      // A fragments (spikes as exact bf16 0/1) for the 3 row-tiles; MFMA accumulate
#pragma unroll
      for (int mt = 0; mt < 3; ++mt) {
        int s = mt * 16 + srow;
        u32 byte = 0;
        if (s < NSc) byte = (spk32[(s * Tc + widx) * 2 + wsel] >> shft) & 0xFFu;
        bf16x8 Af;
#pragma unroll
        for (int j = 0; j < 8; ++j)
          Af[j] = (short)(((byte >> j) & 1u) ? 0x3F80 : 0);
        f32x4& cc = (mt == 0) ? c0 : ((mt == 1) ? c1 : c2);
        cc = __builtin_amdgcn_mfma_f32_16x16x32_bf16(Af, Bhi, cc, 0, 0, 0);
        cc = __builtin_amdgcn_mfma_f32_16x16x32_bf16(Af, Bmid, cc, 0, 0, 0);
        cc = __builtin_amdgcn_mfma_f32_16x16x32_bf16(Af, Blo, cc, 0, 0, 0);
      }
    }
    // write per-wave partial C tiles to LDS (C layout: row=(lane>>4)*4+j2, col=lane&15)
#pragma unroll
    for (int j2 = 0; j2 < 4; ++j2) {
      int row = lgrp * 4 + j2;
      part[((nt * 4 + kqi) * 3 + 0) * 256 + row * 16 + srow] = c0[j2];
      part[((nt * 4 + kqi) * 3 + 1) * 256 + row * 16 + srow] = c1[j2];
      part[((nt * 4 + kqi) * 3 + 2) * 256 + row * 16 + srow] = c2[j2];
    }
    __syncthreads();

    // h-LIF over s = 0..38 (full sequence available) + combine
    const float ba = tf1b[ja], bb = tf1b[jb];
    const float bc2 = (wv < 4) ? tf1b[jc] : 0.0f;
    float hma = 0, hsa = 0, hmb = 0, hsb = 0, hmc = 0, hsc = 0;
#pragma unroll 1
    for (int s = 0; s < NSc; ++s) {
      int mt = s >> 4, row = s & 15;
      int rb = mt * 256 + row * 16;
      float y0 = ba, y1 = bb, y2 = bc2;
#pragma unroll
      for (int kq2 = 0; kq2 < 4; ++kq2) {
        y0 += part[(kq2 * 3) * 256 + rb + ja];              // nt=0, col=ja (0..7)
        y1 += part[(kq2 * 3) * 256 + rb + jb];              // nt=0, col=jb (8..15)
        if (wv < 4) y2 += part[((4 + kq2) * 3) * 256 + rb + (jc - 16)];  // nt=1
      }
      hma = (hma * 0.2f) * ((hma > 0.5f) ? 0.0f : 1.0f) + y0;
      hsa += (hma > 0.5f) ? 1.0f : 0.0f;
      hmb = (hmb * 0.2f) * ((hmb > 0.5f) ? 0.0f : 1.0f) + y1;
      hsb += (hmb > 0.5f) ? 1.0f : 0.0f;
      if (wv < 4) {
        hmc = (hmc * 0.2f) * ((hmc > 0.5f) ? 0.0f : 1.0f) + y2;
        hsc += (hmc > 0.5f) ? 1.0f : 0.0f;
      }
    }
    if (lane == 0) {
      out[b * NCc + ja] = (outS_l[ja] + hsa / (float)NSc) * 0.5f;
      out[b * NCc + jb] = (outS_l[jb] + hsb / (float)NSc) * 0.5f;
      if (wv < 4)
        out[b * NCc + jc] = (outS_l[jc] + hsc / (float)NSc) * 0.5f;
    }
  }
}

extern "C" void kernel_launch(void* const* d_in, const int* in_sizes, int n_in,
                              void* d_out, int out_size, void* d_ws, size_t ws_size,
                              hipStream_t stream) {
  const float* data = (const float*)d_in[0];
  const int*   eiS  = (const int*)d_in[1];
  const int*   eiT  = (const int*)d_in[2];
  const float* c1w  = (const float*)d_in[3];
  const float* c1b  = (const float*)d_in[4];
  const float* c2w  = (const float*)d_in[5];
  const float* c2b  = (const float*)d_in[6];
  const float* f1w  = (const float*)d_in[7];
  const float* f1b  = (const float*)d_in[8];
  const float* tf1w = (const float*)d_in[9];
  const float* tf1b = (const float*)d_in[10];
  float* out = (float*)d_out;
  int* wsI = (int*)d_ws;
  float* wsF = (float*)d_ws;

  prep_graph<<<2, 256, 0, stream>>>(eiS, eiT, wsI, wsF);
  prep_w<<<(NCc * Tc * COc + 255) / 256, 256, 0, stream>>>(f1w, wsF + WS_W1T,
                                                           tf1w, wsF + WS_W2T);
  lif_fused<<<Bc, 512, 0, stream>>>(data,
                                    wsI + WS_ROFF_S, (const int2*)(wsI + WS_EDGE_S),
                                    wsI + WS_ROFF_T, (const int2*)(wsI + WS_EDGE_T),
                                    c1w, c1b, c2w, c2b,
                                    wsF + WS_W1T, f1b, tf1w, tf1b,
                                    out);
}

// Round 19
// 1076.331 us; speedup vs baseline: 3.1133x; 1.2398x over previous
//
#include <hip/hip_runtime.h>

typedef unsigned int u32;
typedef unsigned long long u64;
typedef short bf16x8 __attribute__((ext_vector_type(8)));
typedef float f32x4 __attribute__((ext_vector_type(4)));

#define Bc 256
#define Tc 325
#define NSc 39
#define COc 64
#define NCc 20
#define ESc 117
#define ETc 648

// workspace layout in 4-byte units
#define WS_ROFF_S 0        // 40 ints
#define WS_EDGE_S 64       // 117 int2
#define WS_DINV_S 304      // 39 f
#define WS_ROFF_T 352      // 326 ints
#define WS_EDGE_T 680      // 648 int2
#define WS_DINV_T 1976     // 325 f
#define WS_WF1    2304     // 78 kt x 2 nt x 64 lanes x 12 u32 = 119808 words (bf16 frag hi/mid/lo)

// ---------------- prep: CSR (by dst, interleaved {src, nrm}) ----------------
__global__ void prep_graph(const int* __restrict__ eiS, const int* __restrict__ eiT,
                           int* __restrict__ wsI, float* __restrict__ wsF) {
  const int which = blockIdx.x;
  const int* ei = which ? eiT : eiS;
  const int nE = which ? ETc : ESc;
  const int nN = which ? Tc : NSc;
  int* roff = wsI + (which ? WS_ROFF_T : WS_ROFF_S);
  int2* edge = (int2*)(wsI + (which ? WS_EDGE_T : WS_EDGE_S));
  float* dinv = wsF + (which ? WS_DINV_T : WS_DINV_S);
  const int* src = ei;
  const int* dst = ei + nE;
  for (int n = threadIdx.x; n < nN; n += blockDim.x) {
    int deg = 0, before = 0;
    for (int e = 0; e < nE; ++e) { deg += (dst[e] == n); before += (dst[e] < n); }
    roff[n] = before;
    if (n == nN - 1) roff[nN] = before + deg;
    dinv[n] = (deg > 0) ? (1.0f / sqrtf((float)deg)) : 0.0f;
  }
  __syncthreads();
  for (int n = threadIdx.x; n < nN; n += blockDim.x) {
    int cur = roff[n];
    float dn = dinv[n];
    for (int e = 0; e < nE; ++e) {
      if (dst[e] == n) {
        edge[cur] = make_int2(src[e], __float_as_int(dinv[src[e]] * dn));
        ++cur;
      }
    }
  }
}

// ---------------- prep: build bf16 hi/mid/lo MFMA B-fragments for fc1_w ----------------
__global__ void prep_frag(const float* __restrict__ w1, u32* __restrict__ wf1) {
  int idx = blockIdx.x * 256 + threadIdx.x;   // (kt*2+nt)*64 + lane, total 78*2*64 = 9984
  if (idx < 9984) {
    int lane = idx & 63;
    int tile = idx >> 6;
    int nt = tile & 1, kt = tile >> 1;
    int lgrp = lane >> 4, col = nt * 16 + (lane & 15);
    u32 outw[12];
#pragma unroll
    for (int h = 0; h < 12; ++h) outw[h] = 0u;
#pragma unroll
    for (int j = 0; j < 8; ++j) {
      int k = kt * 32 + lgrp * 8 + j;
      float w = (col < NCc) ? w1[k * NCc + col] : 0.0f;
      u32 bw = __float_as_uint(w);
      u32 hbits = bw & 0xFFFF0000u;
      float r1 = w - __uint_as_float(hbits);
      u32 mbits = __float_as_uint(r1) & 0xFFFF0000u;
      float r2 = r1 - __uint_as_float(mbits);
      u32 lbits = __float_as_uint(r2) & 0xFFFF0000u;
      int wi = j >> 1, sh = (j & 1) * 16;
      outw[0 + wi] |= (hbits >> 16) << sh;
      outw[4 + wi] |= (mbits >> 16) << sh;
      outw[8 + wi] |= (lbits >> 16) << sh;
    }
    u32* dst = wf1 + (size_t)idx * 12;
#pragma unroll
    for (int h = 0; h < 12; ++h) dst[h] = outw[h];
  }
}

// ---------------- fused kernel: 1 batch per block, 512 threads ----------------
__global__ __launch_bounds__(512) __attribute__((amdgpu_waves_per_eu(2, 2)))
void lif_fused(const float* __restrict__ data,
               const int* __restrict__ roffSg, const int2* __restrict__ edgeSg,
               const int* __restrict__ roffTg, const int2* __restrict__ edgeTg,
               const float* __restrict__ c1w, const float* __restrict__ c1b,
               const float* __restrict__ c2w, const float* __restrict__ c2b,
               const u32* __restrict__ wf1, const float* __restrict__ f1b,
               const float* __restrict__ tf1w, const float* __restrict__ tf1b,
               float* __restrict__ out)
{
  __shared__ u64 spk[NSc * Tc];                  // 101400 B: A=[t][39], B=[s][325]
  __shared__ __align__(16) float fAB[13000];     // A: feats/C-parts, B1: 2 planes, B2: C-parts
  __shared__ float outS_l[NCc];
  __shared__ int roffS[NSc + 1];
  __shared__ int2 edgeS[ESc];
  __shared__ int roffT[Tc + 1];
  __shared__ int2 edgeT[ETc];

  const int tid = threadIdx.x;
  const int lane = tid & 63;
  const int wv = tid >> 6;             // 0..7
  const int b = blockIdx.x;
  const float* dbase = data + (size_t)b * (2 * NSc * 2 * Tc);

  for (int i = tid; i < NSc + 1; i += 512) roffS[i] = roffSg[i];
  for (int i = tid; i < ESc; i += 512) edgeS[i] = edgeSg[i];
  for (int i = tid; i < Tc + 1; i += 512) roffT[i] = roffTg[i];
  for (int i = tid; i < ETc; i += 512) edgeT[i] = edgeTg[i];

  // owned LIF outputs
  const int ja = wv, jb = wv + 8, jc = wv + 16;
  const int lgrp = lane >> 4;          // MFMA k-subgroup / C row-group
  const int srow = lane & 15;          // MFMA A-row / C col lane index

  // ============ Phase A: spatial, per 13-t chunk ============
  {
    const float bcv = c1b[lane];
    float cm[5] = {0, 0, 0, 0, 0};
    const float ba = f1b[ja], bb = f1b[jb];
    const float bc2 = (wv < 4) ? f1b[jc] : 0.0f;
    float hma = 0, hsa = 0, hmb = 0, hsb = 0, hmc = 0, hsc = 0;
    const int kqA = wv & 3, ntA = wv >> 2;
    const int ktA0 = (kqA < 2) ? kqA * 20 : 40 + (kqA - 2) * 19;
    const int ktAN = (kqA < 2) ? 20 : 19;
    __syncthreads();

#pragma unroll 1
    for (int ch = 0; ch < 25; ++ch) {
      const int t0 = ch * 13;
      // stage x: fA[c][n][dt16]
#pragma unroll
      for (int it = 0; it < 5; ++it) {
        int idx = tid + it * 512;
        if (idx < 2496) {
          int n = idx >> 6, c = (idx >> 4) & 3, dt = idx & 15;
          float v = 0.0f;
          if (dt < 13) v = dbase[(n + (c >> 1) * NSc) * 650 + (c & 1) * 325 + t0 + dt];
          fAB[c * 624 + n * 16 + dt] = v;
        }
      }
      __syncthreads();
      // 3 hops
#pragma unroll
      for (int k = 1; k <= 3; ++k) {
#pragma unroll
        for (int it = 0; it < 5; ++it) {
          int idx = tid + it * 512;
          if (idx < 2496) {
            int n = idx >> 6, c = (idx >> 4) & 3, dt = idx & 15;
            float v = 0.0f;
            for (int e = roffS[n]; e < roffS[n + 1]; ++e) {
              int2 ed = edgeS[e];
              v = fmaf(__int_as_float(ed.y), fAB[((k - 1) * 4 + c) * 624 + ed.x * 16 + dt], v);
            }
            fAB[(k * 4 + c) * 624 + n * 16 + dt] = v;
          }
        }
        __syncthreads();
      }
      // conv + LIF + ballot -> spk[t][i]
      {
        float wcr[16];
#pragma unroll
        for (int r = 0; r < 16; ++r) wcr[r] = c1w[r * COc + lane];
#pragma unroll
        for (int q = 0; q < 5; ++q) {
          int i = wv + 8 * q;
          if (i < NSc) {
            float za[13];
#pragma unroll
            for (int dt = 0; dt < 13; ++dt) za[dt] = bcv;
#pragma unroll
            for (int r = 0; r < 16; ++r) {
              const float* fp = &fAB[r * 624 + i * 16];
              float w = wcr[r];
              float4 a0 = *(const float4*)fp;
              float4 a1 = *(const float4*)(fp + 4);
              float4 a2 = *(const float4*)(fp + 8);
              float a3 = fp[12];
              za[0] = fmaf(a0.x, w, za[0]);   za[1] = fmaf(a0.y, w, za[1]);
              za[2] = fmaf(a0.z, w, za[2]);   za[3] = fmaf(a0.w, w, za[3]);
              za[4] = fmaf(a1.x, w, za[4]);   za[5] = fmaf(a1.y, w, za[5]);
              za[6] = fmaf(a1.z, w, za[6]);   za[7] = fmaf(a1.w, w, za[7]);
              za[8] = fmaf(a2.x, w, za[8]);   za[9] = fmaf(a2.y, w, za[9]);
              za[10] = fmaf(a2.z, w, za[10]); za[11] = fmaf(a2.w, w, za[11]);
              za[12] = fmaf(a3, w, za[12]);
            }
#pragma unroll
            for (int dt = 0; dt < 13; ++dt) {
              float old = cm[q];
              float m = (old * 0.2f) * ((old > 0.5f) ? 0.0f : 1.0f) + za[dt];
              cm[q] = m;
              u64 wd = __ballot(m > 0.5f);
              if (lane == 0) spk[(t0 + dt) * NSc + i] = wd;
            }
          }
        }
      }
      __syncthreads();
      // fc GEMM via MFMA: M=13(pad16) x N=20(2 nt) x K=2496 (78 kt over 4 kq)
      {
        f32x4 cA = {0, 0, 0, 0};
#pragma unroll 1
        for (int kk = 0; kk < ktAN; ++kk) {
          const int kt = ktA0 + kk;
          const u32* fb = wf1 + ((size_t)(kt * 2 + ntA) * 64 + lane) * 12;
          bf16x8 Bhi = *(const bf16x8*)(fb);
          bf16x8 Bmid = *(const bf16x8*)(fb + 4);
          bf16x8 Blo = *(const bf16x8*)(fb + 8);
          const int widx = kt >> 1, wsel = kt & 1;
          u32 byte = 0;
          if (srow < 13)
            byte = (((const u32*)spk)[((t0 + srow) * NSc + widx) * 2 + wsel] >> (lgrp * 8)) & 0xFFu;
          bf16x8 Af;
#pragma unroll
          for (int j = 0; j < 8; ++j)
            Af[j] = (short)(((byte >> j) & 1u) ? 0x3F80 : 0);
          cA = __builtin_amdgcn_mfma_f32_16x16x32_bf16(Af, Bhi, cA, 0, 0, 0);
          cA = __builtin_amdgcn_mfma_f32_16x16x32_bf16(Af, Bmid, cA, 0, 0, 0);
          cA = __builtin_amdgcn_mfma_f32_16x16x32_bf16(Af, Blo, cA, 0, 0, 0);
        }
        __syncthreads();   // feats reads done (conv) before overwrite below
        // C -> LDS (fAB reused; layout [tile(nt*4+kq)][m-row][n-col])
#pragma unroll
        for (int r = 0; r < 4; ++r) {
          int row = lgrp * 4 + r;
          fAB[(ntA * 4 + kqA) * 256 + row * 16 + srow] = cA[r];
        }
      }
      __syncthreads();
      // h-LIF for owned outputs (sum 4 kq C-tiles)
#pragma unroll
      for (int ds = 0; ds < 13; ++ds) {
        float y0 = ba, y1 = bb, y2 = bc2;
#pragma unroll
        for (int kq2 = 0; kq2 < 4; ++kq2) {
          y0 += fAB[kq2 * 256 + ds * 16 + ja];
          y1 += fAB[kq2 * 256 + ds * 16 + jb];
          if (wv < 4) y2 += fAB[(4 + kq2) * 256 + ds * 16 + (jc - 16)];
        }
        hma = (hma * 0.2f) * ((hma > 0.5f) ? 0.0f : 1.0f) + y0;
        hsa += (hma > 0.5f) ? 1.0f : 0.0f;
        hmb = (hmb * 0.2f) * ((hmb > 0.5f) ? 0.0f : 1.0f) + y1;
        hsb += (hmb > 0.5f) ? 1.0f : 0.0f;
        if (wv < 4) {
          hmc = (hmc * 0.2f) * ((hmc > 0.5f) ? 0.0f : 1.0f) + y2;
          hsc += (hmc > 0.5f) ? 1.0f : 0.0f;
        }
      }
      __syncthreads();
    }
    if (lane == 0) {
      outS_l[ja] = hsa / (float)Tc;
      outS_l[jb] = hsb / (float)Tc;
      if (wv < 4) outS_l[jc] = hsc / (float)Tc;
    }
  }
  __syncthreads();

  // ============ Phase B1: temporal conv chain, 2 s-steps per barrier group ============
  {
    float wc[16];
#pragma unroll
    for (int r = 0; r < 16; ++r) wc[r] = c2w[r * COc + lane];
    const float bcv = c2b[lane];
    float tm[41];
#pragma unroll
    for (int q = 0; q < 41; ++q) tm[q] = 0.0f;

#pragma unroll 1
    for (int pr = 0; pr < 20; ++pr) {
      const int sA = pr * 2;
      const int pN = (sA + 1 < NSc) ? 2 : 1;
      const int items = pN * 1300;
#pragma unroll
      for (int it = 0; it < 6; ++it) {
        int idx = tid + it * 512;
        if (idx < items) {
          int p = (idx >= 1300) ? 1 : 0;
          int q2 = idx - p * 1300;
          int c = q2 / 325, t = q2 - c * 325;
          fAB[p * 6500 + t * 20 + c] =
              dbase[((sA + p) + (c >> 1) * NSc) * 650 + (c & 1) * 325 + t];
        }
      }
      __syncthreads();
#pragma unroll
      for (int k = 1; k <= 3; ++k) {
#pragma unroll
        for (int it = 0; it < 6; ++it) {
          int idx = tid + it * 512;
          if (idx < items) {
            int p = (idx >= 1300) ? 1 : 0;
            int q2 = idx - p * 1300;
            int t = q2 >> 2, c = q2 & 3;
            float v = 0.0f;
            for (int e = roffT[t]; e < roffT[t + 1]; ++e) {
              int2 ed = edgeT[e];
              v = fmaf(__int_as_float(ed.y), fAB[p * 6500 + ed.x * 20 + (k - 1) * 4 + c], v);
            }
            fAB[p * 6500 + t * 20 + k * 4 + c] = v;
          }
        }
        __syncthreads();
      }
#pragma unroll
      for (int q = 0; q < 41; ++q) {
        int i = wv + 8 * q;
        if (i < Tc) {
          float m = tm[q];
#pragma unroll
          for (int p = 0; p < 2; ++p) {
            if (p < pN) {
              const float4* f4 = (const float4*)&fAB[p * 6500 + i * 20];
              float4 f0 = f4[0], f1 = f4[1], f2 = f4[2], f3 = f4[3];
              float acc = bcv;
              acc = fmaf(f0.x, wc[0], acc);  acc = fmaf(f0.y, wc[1], acc);
              acc = fmaf(f0.z, wc[2], acc);  acc = fmaf(f0.w, wc[3], acc);
              acc = fmaf(f1.x, wc[4], acc);  acc = fmaf(f1.y, wc[5], acc);
              acc = fmaf(f1.z, wc[6], acc);  acc = fmaf(f1.w, wc[7], acc);
              acc = fmaf(f2.x, wc[8], acc);  acc = fmaf(f2.y, wc[9], acc);
              acc = fmaf(f2.z, wc[10], acc); acc = fmaf(f2.w, wc[11], acc);
              acc = fmaf(f3.x, wc[12], acc); acc = fmaf(f3.y, wc[13], acc);
              acc = fmaf(f3.z, wc[14], acc); acc = fmaf(f3.w, wc[15], acc);
              m = (m * 0.2f) * ((m > 0.5f) ? 0.0f : 1.0f) + acc;
              u64 wd = __ballot(m > 0.5f);
              if (lane == 0) spk[(sA + p) * Tc + i] = wd;
            }
          }
          tm[q] = m;
        }
      }
      __syncthreads();
    }
  }

  // ============ Phase B2: temporal fc via MFMA (bf16 hi/mid/lo split) + h-LIF + combine ============
  {
    const u32* spk32 = (const u32*)spk;
    float* part = fAB;                 // [2 nt][4 kq][3 mt][16 row][16 col] = 6144 f
    const int kqi = wv & 3;
    const int nt = wv >> 2;
    const int col = nt * 16 + srow;
    const int kt0 = (kqi < 2) ? kqi * 163 : 326 + (kqi - 2) * 162;
    const int ktN = (kqi < 2) ? 163 : 162;

    f32x4 c0 = {0, 0, 0, 0}, c1 = {0, 0, 0, 0}, c2 = {0, 0, 0, 0};

#pragma unroll 1
    for (int kk = 0; kk < ktN; ++kk) {
      const int kt = kt0 + kk;
      const int kbase = kt * 32 + lgrp * 8;
      bf16x8 Bhi, Bmid, Blo;
#pragma unroll
      for (int j = 0; j < 8; ++j) {
        float w = (col < NCc) ? tf1w[(kbase + j) * NCc + col] : 0.0f;
        u32 bw = __float_as_uint(w);
        u32 hbits = bw & 0xFFFF0000u;
        float r1 = w - __uint_as_float(hbits);
        u32 mbits = __float_as_uint(r1) & 0xFFFF0000u;
        float r2 = r1 - __uint_as_float(mbits);
        Bhi[j] = (short)(hbits >> 16);
        Bmid[j] = (short)(mbits >> 16);
        Blo[j] = (short)(__float_as_uint(r2) >> 16);
      }
      const int widx = (kt >> 1);
      const int wsel = (kt & 1);
      const int shft = lgrp * 8;
#pragma unroll
      for (int mt = 0; mt < 3; ++mt) {
        int s = mt * 16 + srow;
        u32 byte = 0;
        if (s < NSc) byte = (spk32[(s * Tc + widx) * 2 + wsel] >> shft) & 0xFFu;
        bf16x8 Af;
#pragma unroll
        for (int j = 0; j < 8; ++j)
          Af[j] = (short)(((byte >> j) & 1u) ? 0x3F80 : 0);
        f32x4& cc = (mt == 0) ? c0 : ((mt == 1) ? c1 : c2);
        cc = __builtin_amdgcn_mfma_f32_16x16x32_bf16(Af, Bhi, cc, 0, 0, 0);
        cc = __builtin_amdgcn_mfma_f32_16x16x32_bf16(Af, Bmid, cc, 0, 0, 0);
        cc = __builtin_amdgcn_mfma_f32_16x16x32_bf16(Af, Blo, cc, 0, 0, 0);
      }
    }
#pragma unroll
    for (int j2 = 0; j2 < 4; ++j2) {
      int row = lgrp * 4 + j2;
      part[((nt * 4 + kqi) * 3 + 0) * 256 + row * 16 + srow] = c0[j2];
      part[((nt * 4 + kqi) * 3 + 1) * 256 + row * 16 + srow] = c1[j2];
      part[((nt * 4 + kqi) * 3 + 2) * 256 + row * 16 + srow] = c2[j2];
    }
    __syncthreads();

    const float ba = tf1b[ja], bb = tf1b[jb];
    const float bc2 = (wv < 4) ? tf1b[jc] : 0.0f;
    float hma = 0, hsa = 0, hmb = 0, hsb = 0, hmc = 0, hsc = 0;
#pragma unroll 1
    for (int s = 0; s < NSc; ++s) {
      int mt = s >> 4, row = s & 15;
      int rb = mt * 256 + row * 16;
      float y0 = ba, y1 = bb, y2 = bc2;
#pragma unroll
      for (int kq2 = 0; kq2 < 4; ++kq2) {
        y0 += part[(kq2 * 3) * 256 + rb + ja];
        y1 += part[(kq2 * 3) * 256 + rb + jb];
        if (wv < 4) y2 += part[((4 + kq2) * 3) * 256 + rb + (jc - 16)];
      }
      hma = (hma * 0.2f) * ((hma > 0.5f) ? 0.0f : 1.0f) + y0;
      hsa += (hma > 0.5f) ? 1.0f : 0.0f;
      hmb = (hmb * 0.2f) * ((hmb > 0.5f) ? 0.0f : 1.0f) + y1;
      hsb += (hmb > 0.5f) ? 1.0f : 0.0f;
      if (wv < 4) {
        hmc = (hmc * 0.2f) * ((hmc > 0.5f) ? 0.0f : 1.0f) + y2;
        hsc += (hmc > 0.5f) ? 1.0f : 0.0f;
      }
    }
    if (lane == 0) {
      out[b * NCc + ja] = (outS_l[ja] + hsa / (float)NSc) * 0.5f;
      out[b * NCc + jb] = (outS_l[jb] + hsb / (float)NSc) * 0.5f;
      if (wv < 4)
        out[b * NCc + jc] = (outS_l[jc] + hsc / (float)NSc) * 0.5f;
    }
  }
}

extern "C" void kernel_launch(void* const* d_in, const int* in_sizes, int n_in,
                              void* d_out, int out_size, void* d_ws, size_t ws_size,
                              hipStream_t stream) {
  const float* data = (const float*)d_in[0];
  const int*   eiS  = (const int*)d_in[1];
  const int*   eiT  = (const int*)d_in[2];
  const float* c1w  = (const float*)d_in[3];
  const float* c1b  = (const float*)d_in[4];
  const float* c2w  = (const float*)d_in[5];
  const float* c2b  = (const float*)d_in[6];
  const float* f1w  = (const float*)d_in[7];
  const float* f1b  = (const float*)d_in[8];
  const float* tf1w = (const float*)d_in[9];
  const float* tf1b = (const float*)d_in[10];
  float* out = (float*)d_out;
  int* wsI = (int*)d_ws;
  u32* wsU = (u32*)d_ws;

  prep_graph<<<2, 256, 0, stream>>>(eiS, eiT, wsI, (float*)d_ws);
  prep_frag<<<(9984 + 255) / 256, 256, 0, stream>>>(f1w, wsU + WS_WF1);
  lif_fused<<<Bc, 512, 0, stream>>>(data,
                                    wsI + WS_ROFF_S, (const int2*)(wsI + WS_EDGE_S),
                                    wsI + WS_ROFF_T, (const int2*)(wsI + WS_EDGE_T),
                                    c1w, c1b, c2w, c2b,
                                    wsU + WS_WF1, f1b, tf1w, tf1b,
                                    out);
}